// Round 11
// baseline (348.095 us; speedup 1.0000x reference)
//
#include <hip/hip_runtime.h>
#include <hip/hip_bf16.h>

#define C 256
#define NOUT 1280
#define BK 32

typedef __attribute__((ext_vector_type(8))) short bf16x8;
typedef __attribute__((ext_vector_type(4))) float f32x4;
typedef __attribute__((ext_vector_type(4))) unsigned short us4;

#define GLL16(g, l)                                                         \
  __builtin_amdgcn_global_load_lds(                                         \
      (const __attribute__((address_space(1))) void*)(g),                   \
      (__attribute__((address_space(3))) void*)(l), 16, 0, 0)

__device__ __forceinline__ float bf2f(unsigned short u) {
  return __uint_as_float(((unsigned int)u) << 16);
}
__device__ __forceinline__ unsigned short f2bf(float f) {
  unsigned int x = __float_as_uint(f);
  unsigned int lsb = (x >> 16) & 1u;
  x += 0x7fffu + lsb;  // round-to-nearest-even
  return (unsigned short)(x >> 16);
}

// Fused prep.
// blocks [0,80): W transpose via LDS (coalesced both sides):
//   WT2[n][k] = bf16(W_m[k][c]), n = m*256+c. 5 matrices x 16 tiles of 64x64.
// [80, 80+rowsPad/4): X->bf16 rows + ax2[row] = dot(X,w2).  rest: cnt = 0.
__global__ void k_pre(const float* __restrict__ X, const float* __restrict__ rel,
                      const float* __restrict__ root, const float* __restrict__ attw,
                      unsigned short* __restrict__ Xbf, unsigned short* __restrict__ WT2,
                      float* __restrict__ ax2, int* __restrict__ cnt,
                      int N, int rowsPad) {
  __shared__ float tw[64][65];
  int b = blockIdx.x, t = threadIdx.x;
  if (b < 80) {
    int m = b >> 4, tile = b & 15;
    int ti = tile >> 2, tj = tile & 3;           // ti: k-tile, tj: c-tile
    const float* W = (m == 0) ? root : (rel + (size_t)(m - 1) * C * C);
    int row = t >> 2, cj = (t & 3) * 16;         // row = k within tile
    const float* src = W + (size_t)(ti * 64 + row) * C + tj * 64 + cj;
#pragma unroll
    for (int j = 0; j < 4; ++j) {
      float4 v = reinterpret_cast<const float4*>(src)[j];
      tw[row][cj + j * 4 + 0] = v.x;
      tw[row][cj + j * 4 + 1] = v.y;
      tw[row][cj + j * 4 + 2] = v.z;
      tw[row][cj + j * 4 + 3] = v.w;
    }
    __syncthreads();
    int c = t >> 2, k0 = (t & 3) * 16;           // c within tile
    int n = m * 256 + tj * 64 + c;
    unsigned short o[16];
#pragma unroll
    for (int k = 0; k < 16; ++k) o[k] = f2bf(tw[k0 + k][c]);
#pragma unroll
    for (int j = 0; j < 4; ++j)
      *reinterpret_cast<us4*>(WT2 + (size_t)n * C + ti * 64 + k0 + j * 4) =
          *reinterpret_cast<us4*>(&o[j * 4]);
  } else if (b < 80 + (rowsPad >> 2)) {
    int row = (b - 80) * 4 + (t >> 6);
    int lane = t & 63;
    if (row < N) {
      float4 v = reinterpret_cast<const float4*>(X + (size_t)row * C)[lane];
      float4 w2 = reinterpret_cast<const float4*>(attw + C)[lane];
      us4 o;
      o.x = f2bf(v.x); o.y = f2bf(v.y); o.z = f2bf(v.z); o.w = f2bf(v.w);
      reinterpret_cast<us4*>(Xbf)[(size_t)row * 64 + lane] = o;
      float p = v.x * w2.x + v.y * w2.y + v.z * w2.z + v.w * w2.w;
#pragma unroll
      for (int m2 = 32; m2 >= 1; m2 >>= 1) p += __shfl_xor(p, m2);
      if (lane == 0) ax2[row] = p;
    } else if (row < rowsPad) {
      us4 z; z.x = 0; z.y = 0; z.z = 0; z.w = 0;
      reinterpret_cast<us4*>(Xbf)[(size_t)row * 64 + lane] = z;
      if (lane == 0) ax2[row] = 0.f;
    }
  } else {
    int i = (b - 80 - (rowsPad >> 2)) * 256 + t;
    if (i < N) cnt[i] = 0;
  }
}

__global__ void k_hist(const int* __restrict__ edst, int* __restrict__ cnt, int E) {
  int e = blockIdx.x * blockDim.x + threadIdx.x;
  if (e < E) atomicAdd(cnt + edst[e], 1);
}

// Single-block exclusive scan of cnt[0..N) -> rp, cursor; rp[N] = total.
__global__ __launch_bounds__(1024) void k_scan(const int* __restrict__ cnt,
                                               int* __restrict__ rp,
                                               int* __restrict__ cursor, int n) {
  __shared__ int s[1024];
  int t = threadIdx.x;
  int chunk = (n + 1023) >> 10;
  int lo = t * chunk, hi = min(lo + chunk, n);
  int sum = 0;
  for (int i = lo; i < hi; ++i) sum += cnt[i];
  s[t] = sum;
  __syncthreads();
  for (int off = 1; off < 1024; off <<= 1) {
    int add = (t >= off) ? s[t - off] : 0;
    __syncthreads();
    s[t] += add;
    __syncthreads();
  }
  int run = s[t] - sum;   // exclusive prefix of this chunk
  for (int i = lo; i < hi; ++i) {
    int v = cnt[i];
    rp[i] = run;
    cursor[i] = run;
    run += v;
  }
  if (t == 1023) rp[n] = s[1023];
}

__global__ void k_fill(const int* __restrict__ esrc, const int* __restrict__ edst,
                       const int* __restrict__ etype, int* __restrict__ cursor,
                       unsigned int* __restrict__ sorted, int E) {
  int e = blockIdx.x * blockDim.x + threadIdx.x;
  if (e >= E) return;
  int d = edst[e];
  int pos = atomicAdd(cursor + d, 1);
  sorted[pos] = (unsigned int)esrc[e] | ((unsigned int)etype[e] << 28);
}

// Y = Xbf @ WT2^T, M=rowsPad N=1280 K=256, Y bf16 [rowsPad][1280].
// 128x128 tile, 2-phase dbuf, GLL16 staging, 2-way-max XOR swizzle, XCD
// chunked swizzle, fully unrolled 8-step K loop. Epilogue: acc -> LDS
// (granule-rotation swizzle) -> 16B coalesced Y stores.
__global__ __launch_bounds__(256) void k_gemm(
    const unsigned short* __restrict__ Xbf, const unsigned short* __restrict__ WT2,
    unsigned short* __restrict__ Y, int rowsPad) {
  __shared__ unsigned short smem[16384];          // 32KB: A dbuf 16KB | B dbuf 16KB
  unsigned short* ldsA = smem;                    // [2][4096]
  unsigned short* ldsB = smem + 8192;             // [2][4096]
  int tid = threadIdx.x;
  int wave = tid >> 6, lane = tid & 63;

  // bijective chunked XCD swizzle
  int nwg = gridDim.x, orig = blockIdx.x;
  int q = nwg >> 3, r = nwg & 7;
  int xcd = orig & 7, lin = orig >> 3;
  int wgid = (xcd < r ? xcd * (q + 1) : r * (q + 1) + (xcd - r) * q) + lin;
  int mblk = wgid / 10, nblk = wgid - mblk * 10;
  int row0 = mblk * 128, col0 = nblk * 128;
  int wr = wave >> 1, wc = wave & 1, lcol = lane & 15;

  // staging: tile 8KB = 8 chunks of 1KB; wave stages chunks 2w,2w+1 of A and B
  const unsigned short* aSrc[2];
  const unsigned short* bSrc[2];
  int ldsOfs[2];
#pragma unroll
  for (int c2 = 0; c2 < 2; ++c2) {
    int off = (wave * 2 + c2) * 1024 + lane * 16;
    int rr = off >> 6;
    int lg8 = (((off >> 4) & 3) ^ ((rr >> 1) & 3)) * 8;   // inverse-swizzled src
    aSrc[c2] = Xbf + (size_t)(row0 + rr) * C + lg8;
    bSrc[c2] = WT2 + (size_t)(col0 + rr) * C + lg8;
    ldsOfs[c2] = (wave * 2 + c2) * 1024;
  }

  // ds_read byte offsets (swizzled)
  int aoff[4], boff[4];
  int kb = (lane >> 4) * 16;
#pragma unroll
  for (int i = 0; i < 4; ++i) {
    int ar = wr * 64 + i * 16 + lcol;
    aoff[i] = ar * 64 + (kb ^ (((ar >> 1) & 3) << 4));
    int bc = wc * 64 + i * 16 + lcol;
    boff[i] = bc * 64 + (kb ^ (((bc >> 1) & 3) << 4));
  }

  f32x4 acc[4][4];
#pragma unroll
  for (int i = 0; i < 4; ++i)
#pragma unroll
    for (int j = 0; j < 4; ++j) {
      f32x4 z; z[0] = 0.f; z[1] = 0.f; z[2] = 0.f; z[3] = 0.f;
      acc[i][j] = z;
    }

  auto stage = [&](int buf, int ks) {
    int kofs = ks * BK;
#pragma unroll
    for (int c2 = 0; c2 < 2; ++c2) {
      GLL16(aSrc[c2] + kofs, (char*)(ldsA + buf * 4096) + ldsOfs[c2]);
      GLL16(bSrc[c2] + kofs, (char*)(ldsB + buf * 4096) + ldsOfs[c2]);
    }
  };

  stage(0, 0);
  __syncthreads();

#pragma unroll
  for (int ks = 0; ks < 8; ++ks) {
    int cur = ks & 1;
    if (ks + 1 < 8) stage(cur ^ 1, ks + 1);
    bf16x8 af[4], bfr[4];
#pragma unroll
    for (int i = 0; i < 4; ++i) {
      af[i]  = *reinterpret_cast<const bf16x8*>((const char*)(ldsA + cur * 4096) + aoff[i]);
      bfr[i] = *reinterpret_cast<const bf16x8*>((const char*)(ldsB + cur * 4096) + boff[i]);
    }
#pragma unroll
    for (int mr = 0; mr < 4; ++mr)
#pragma unroll
      for (int nc = 0; nc < 4; ++nc)
        acc[mr][nc] = __builtin_amdgcn_mfma_f32_16x16x32_bf16(af[mr], bfr[nc], acc[mr][nc], 0, 0, 0);
    __syncthreads();
  }

  // epilogue: smem as logical [128][128] bf16 with granule rotation
  // phys granule p = ((c>>3) + r) & 15; entry = r*128 + p*8 + (c&7)
  int lrow4 = (lane >> 4) * 4;
#pragma unroll
  for (int mr = 0; mr < 4; ++mr)
#pragma unroll
    for (int nc = 0; nc < 4; ++nc)
#pragma unroll
      for (int reg = 0; reg < 4; ++reg) {
        int rr = wr * 64 + mr * 16 + lrow4 + reg;
        int cc = wc * 64 + nc * 16 + lcol;
        smem[rr * 128 + ((((cc >> 3) + rr) & 15) << 3) + (cc & 7)] =
            f2bf(acc[mr][nc][reg]);
      }
  __syncthreads();
#pragma unroll
  for (int rnd = 0; rnd < 8; ++rnd) {
    int rr = rnd * 16 + (tid >> 4);
    int g = tid & 15;
    int p = (g + rr) & 15;
    bf16x8 v = *reinterpret_cast<const bf16x8*>(smem + rr * 128 + p * 8);
    *reinterpret_cast<bf16x8*>(Y + (size_t)(row0 + rr) * NOUT + col0 + g * 8) = v;
  }
}

#define ACC(u, v)                                                            \
  do {                                                                       \
    float f0 = bf2f((v).x), f1 = bf2f((v).y), f2 = bf2f((v).z), f3 = bf2f((v).w); \
    switch ((u) >> 28) {                                                     \
      case 0: a0.x += f0; a0.y += f1; a0.z += f2; a0.w += f3; ++c0; break;   \
      case 1: a1.x += f0; a1.y += f1; a1.z += f2; a1.w += f3; ++c1; break;   \
      case 2: a2.x += f0; a2.y += f1; a2.z += f2; a2.w += f3; ++c2; break;   \
      default: a3.x += f0; a3.y += f1; a3.z += f2; a3.w += f3; ++c3; break;  \
    }                                                                        \
  } while (0)

// Fused gather+gate. One wave per dst: mean per-relation Y slices (+root+bias)
// -> u0; a = sigmoid(dot(u0,w1)+ax2+ab); out = tanh(u0)*a + X*(1-a).
__global__ void k_gg(const unsigned short* __restrict__ Y,
                     const unsigned int* __restrict__ sorted,
                     const int* __restrict__ rp, const float* __restrict__ X,
                     const float* __restrict__ bias, const float* __restrict__ attw,
                     const float* __restrict__ abp, const float* __restrict__ ax2,
                     float* __restrict__ out, int N) {
  int wave = threadIdx.x >> 6, lane = threadIdx.x & 63;
  int dst = blockIdx.x * 4 + wave;
  if (dst >= N) return;
  const us4* Yv = reinterpret_cast<const us4*>(Y);   // row stride 320 us4

  float4 a0 = make_float4(0, 0, 0, 0), a1 = a0, a2 = a0, a3 = a0;
  int c0 = 0, c1 = 0, c2 = 0, c3 = 0;
  int s = rp[dst], e2 = rp[dst + 1];

#define YIDX(u) ((size_t)((u) & 0x0FFFFFFFu) * 320 + (((u) >> 28) + 1) * 64 + lane)
  int e = s;
  for (; e + 8 <= e2; e += 8) {
    unsigned int u0 = sorted[e],     u1 = sorted[e + 1], u2 = sorted[e + 2], u3 = sorted[e + 3];
    unsigned int u4 = sorted[e + 4], u5 = sorted[e + 5], u6 = sorted[e + 6], u7 = sorted[e + 7];
    us4 v0 = Yv[YIDX(u0)], v1 = Yv[YIDX(u1)], v2 = Yv[YIDX(u2)], v3 = Yv[YIDX(u3)];
    us4 v4 = Yv[YIDX(u4)], v5 = Yv[YIDX(u5)], v6 = Yv[YIDX(u6)], v7 = Yv[YIDX(u7)];
    ACC(u0, v0); ACC(u1, v1); ACC(u2, v2); ACC(u3, v3);
    ACC(u4, v4); ACC(u5, v5); ACC(u6, v6); ACC(u7, v7);
  }
  for (; e + 4 <= e2; e += 4) {
    unsigned int u0 = sorted[e], u1 = sorted[e + 1], u2 = sorted[e + 2], u3 = sorted[e + 3];
    us4 v0 = Yv[YIDX(u0)], v1 = Yv[YIDX(u1)], v2 = Yv[YIDX(u2)], v3 = Yv[YIDX(u3)];
    ACC(u0, v0); ACC(u1, v1); ACC(u2, v2); ACC(u3, v3);
  }
  for (; e < e2; ++e) {
    unsigned int u = sorted[e];
    us4 v = Yv[YIDX(u)];
    ACC(u, v);
  }
#undef YIDX

  float s0 = 1.0f / (float)max(c0, 1);
  float s1 = 1.0f / (float)max(c1, 1);
  float s2 = 1.0f / (float)max(c2, 1);
  float s3 = 1.0f / (float)max(c3, 1);
  us4 rt = Yv[(size_t)dst * 320 + lane];              // root slice (m=0)
  float4 bi = reinterpret_cast<const float4*>(bias)[lane];
  float4 w1 = reinterpret_cast<const float4*>(attw)[lane];
  float4 u0;
  u0.x = a0.x * s0 + a1.x * s1 + a2.x * s2 + a3.x * s3 + bf2f(rt.x) + bi.x;
  u0.y = a0.y * s0 + a1.y * s1 + a2.y * s2 + a3.y * s3 + bf2f(rt.y) + bi.y;
  u0.z = a0.z * s0 + a1.z * s1 + a2.z * s2 + a3.z * s3 + bf2f(rt.z) + bi.z;
  u0.w = a0.w * s0 + a1.w * s1 + a2.w * s2 + a3.w * s3 + bf2f(rt.w) + bi.w;

  float p = u0.x * w1.x + u0.y * w1.y + u0.z * w1.z + u0.w * w1.w;
#pragma unroll
  for (int m2 = 32; m2 >= 1; m2 >>= 1) p += __shfl_xor(p, m2);
  float a = 1.0f / (1.0f + expf(-(p + ax2[dst] + abp[0])));
  float b = 1.0f - a;
  float4 x4 = reinterpret_cast<const float4*>(X + (size_t)dst * C)[lane];
  float4 h;
  h.x = tanhf(u0.x) * a + x4.x * b;
  h.y = tanhf(u0.y) * a + x4.y * b;
  h.z = tanhf(u0.z) * a + x4.z * b;
  h.w = tanhf(u0.w) * a + x4.w * b;
  reinterpret_cast<float4*>(out + (size_t)dst * C)[lane] = h;
}

extern "C" void kernel_launch(void* const* d_in, const int* in_sizes, int n_in,
                              void* d_out, int out_size, void* d_ws, size_t ws_size,
                              hipStream_t stream) {
  const float* X     = (const float*)d_in[0];
  const int*   eidx  = (const int*)d_in[1];
  const int*   etype = (const int*)d_in[2];
  const float* rel   = (const float*)d_in[3];
  const float* root  = (const float*)d_in[4];
  const float* bias  = (const float*)d_in[5];
  const float* attw  = (const float*)d_in[6];
  const float* ab    = (const float*)d_in[7];
  float* out = (float*)d_out;

  int N = in_sizes[0] / C;                // 50000
  int E = in_sizes[2];                    // 800000
  int rowsPad = ((N + 127) / 128) * 128;  // 50048
  const int* esrc = eidx;
  const int* edst = eidx + E;

  char* w = (char*)d_ws;
  size_t off = 0;
  auto alloc = [&](size_t bytes) -> void* {
    void* p = w + off;
    off += (bytes + 255) & ~(size_t)255;
    return p;
  };
  unsigned short* Y    = (unsigned short*)alloc((size_t)rowsPad * NOUT * 2);  // 128 MB
  unsigned short* Xbf  = (unsigned short*)alloc((size_t)rowsPad * C * 2);
  unsigned short* WT2  = (unsigned short*)alloc((size_t)NOUT * C * 2);
  float* ax2  = (float*)alloc((size_t)rowsPad * 4);
  int* cnt    = (int*)alloc((size_t)N * 4);
  int* rp     = (int*)alloc((size_t)(N + 1) * 4);
  int* cursor = (int*)alloc((size_t)N * 4);
  unsigned int* sorted = (unsigned int*)alloc((size_t)E * 4);

  int preBlocks = 80 + (rowsPad >> 2) + (N + 255) / 256;
  k_pre<<<preBlocks, 256, 0, stream>>>(X, rel, root, attw, Xbf, WT2, ax2, cnt, N, rowsPad);
  k_hist<<<(E + 255) / 256, 256, 0, stream>>>(edst, cnt, E);
  k_scan<<<1, 1024, 0, stream>>>(cnt, rp, cursor, N);
  k_fill<<<(E + 255) / 256, 256, 0, stream>>>(esrc, edst, etype, cursor, sorted, E);
  k_gemm<<<(rowsPad / 128) * 10, 256, 0, stream>>>(Xbf, WT2, Y, rowsPad);
  k_gg<<<(N + 3) / 4, 256, 0, stream>>>(Y, sorted, rp, X, bias, attw, ab, ax2, out, N);
}

// Round 12
// 254.793 us; speedup vs baseline: 1.3662x; 1.3662x over previous
//
#include <hip/hip_runtime.h>
#include <hip/hip_bf16.h>

#define C 256
#define NOUT 1280
#define BK 32

typedef __attribute__((ext_vector_type(8))) short bf16x8;
typedef __attribute__((ext_vector_type(4))) float f32x4;
typedef __attribute__((ext_vector_type(4))) unsigned short us4;

#define GLL16(g, l)                                                         \
  __builtin_amdgcn_global_load_lds(                                         \
      (const __attribute__((address_space(1))) void*)(g),                   \
      (__attribute__((address_space(3))) void*)(l), 16, 0, 0)

__device__ __forceinline__ float bf2f(unsigned short u) {
  return __uint_as_float(((unsigned int)u) << 16);
}
__device__ __forceinline__ unsigned short f2bf(float f) {
  unsigned int x = __float_as_uint(f);
  unsigned int lsb = (x >> 16) & 1u;
  x += 0x7fffu + lsb;  // round-to-nearest-even
  return (unsigned short)(x >> 16);
}

// Fused prep.
// blocks [0,80): W transpose via LDS (coalesced both sides):
//   WT2[n][k] = bf16(W_m[k][c]), n = m*256+c. 5 matrices x 16 tiles of 64x64.
// [80, 80+rowsPad/4): X->bf16 rows + ax2[row] = dot(X,w2).  rest: cnt = 0.
__global__ void k_pre(const float* __restrict__ X, const float* __restrict__ rel,
                      const float* __restrict__ root, const float* __restrict__ attw,
                      unsigned short* __restrict__ Xbf, unsigned short* __restrict__ WT2,
                      float* __restrict__ ax2, int* __restrict__ cnt,
                      int N, int rowsPad) {
  __shared__ float tw[64][65];
  int b = blockIdx.x, t = threadIdx.x;
  if (b < 80) {
    int m = b >> 4, tile = b & 15;
    int ti = tile >> 2, tj = tile & 3;           // ti: k-tile, tj: c-tile
    const float* W = (m == 0) ? root : (rel + (size_t)(m - 1) * C * C);
    int row = t >> 2, cj = (t & 3) * 16;         // row = k within tile
    const float* src = W + (size_t)(ti * 64 + row) * C + tj * 64 + cj;
#pragma unroll
    for (int j = 0; j < 4; ++j) {
      float4 v = reinterpret_cast<const float4*>(src)[j];
      tw[row][cj + j * 4 + 0] = v.x;
      tw[row][cj + j * 4 + 1] = v.y;
      tw[row][cj + j * 4 + 2] = v.z;
      tw[row][cj + j * 4 + 3] = v.w;
    }
    __syncthreads();
    int c = t >> 2, k0 = (t & 3) * 16;           // c within tile
    int n = m * 256 + tj * 64 + c;
    unsigned short o[16];
#pragma unroll
    for (int k = 0; k < 16; ++k) o[k] = f2bf(tw[k0 + k][c]);
#pragma unroll
    for (int j = 0; j < 4; ++j)
      *reinterpret_cast<us4*>(WT2 + (size_t)n * C + ti * 64 + k0 + j * 4) =
          *reinterpret_cast<us4*>(&o[j * 4]);
  } else if (b < 80 + (rowsPad >> 2)) {
    int row = (b - 80) * 4 + (t >> 6);
    int lane = t & 63;
    if (row < N) {
      float4 v = reinterpret_cast<const float4*>(X + (size_t)row * C)[lane];
      float4 w2 = reinterpret_cast<const float4*>(attw + C)[lane];
      us4 o;
      o.x = f2bf(v.x); o.y = f2bf(v.y); o.z = f2bf(v.z); o.w = f2bf(v.w);
      reinterpret_cast<us4*>(Xbf)[(size_t)row * 64 + lane] = o;
      float p = v.x * w2.x + v.y * w2.y + v.z * w2.z + v.w * w2.w;
#pragma unroll
      for (int m2 = 32; m2 >= 1; m2 >>= 1) p += __shfl_xor(p, m2);
      if (lane == 0) ax2[row] = p;
    } else if (row < rowsPad) {
      us4 z; z.x = 0; z.y = 0; z.z = 0; z.w = 0;
      reinterpret_cast<us4*>(Xbf)[(size_t)row * 64 + lane] = z;
      if (lane == 0) ax2[row] = 0.f;
    }
  } else {
    int i = (b - 80 - (rowsPad >> 2)) * 256 + t;
    if (i < N) cnt[i] = 0;
  }
}

__global__ void k_hist(const int* __restrict__ edst, int* __restrict__ cnt, int E) {
  int e = blockIdx.x * blockDim.x + threadIdx.x;
  if (e < E) atomicAdd(cnt + edst[e], 1);
}

__global__ void k_scan1(const int* __restrict__ cnt, int* __restrict__ rp,
                        int* __restrict__ bsum, int n) {
  __shared__ int s[512];
  int t = threadIdx.x;
  int i = blockIdx.x * 512 + t;
  int v = (i < n) ? cnt[i] : 0;
  s[t] = v;
  __syncthreads();
  for (int off = 1; off < 512; off <<= 1) {
    int add = (t >= off) ? s[t - off] : 0;
    __syncthreads();
    s[t] += add;
    __syncthreads();
  }
  if (i < n) rp[i] = s[t] - v;
  if (t == 511) bsum[blockIdx.x] = s[511];
}

__global__ void k_scan2(const int* __restrict__ bsum, int* __restrict__ boff,
                        int* __restrict__ rp, int nb, int n) {
  if (threadIdx.x == 0) {
    int run = 0;
    for (int b = 0; b < nb; ++b) { boff[b] = run; run += bsum[b]; }
    rp[n] = run;
  }
}

__global__ void k_scan3(int* __restrict__ rp, const int* __restrict__ boff,
                        int* __restrict__ cursor, int n) {
  int i = blockIdx.x * 512 + threadIdx.x;
  if (i < n) {
    int v = rp[i] + boff[blockIdx.x];
    rp[i] = v;
    cursor[i] = v;
  }
}

__global__ void k_fill(const int* __restrict__ esrc, const int* __restrict__ edst,
                       const int* __restrict__ etype, int* __restrict__ cursor,
                       unsigned int* __restrict__ sorted, int E) {
  int e = blockIdx.x * blockDim.x + threadIdx.x;
  if (e >= E) return;
  int d = edst[e];
  int pos = atomicAdd(cursor + d, 1);
  sorted[pos] = (unsigned int)esrc[e] | ((unsigned int)etype[e] << 28);
}

// Y = Xbf @ WT2^T, M=rowsPad N=1280 K=256, Y bf16 [rowsPad][1280].
// 128x128 tile, 2-phase dbuf, GLL16 staging, 2-way-max XOR swizzle, XCD
// chunked swizzle, fully unrolled 8-step K loop. Epilogue: acc -> LDS
// (granule-rotation swizzle) -> 16B coalesced Y stores.
__global__ __launch_bounds__(256) void k_gemm(
    const unsigned short* __restrict__ Xbf, const unsigned short* __restrict__ WT2,
    unsigned short* __restrict__ Y, int rowsPad) {
  __shared__ unsigned short smem[16384];          // 32KB: A dbuf 16KB | B dbuf 16KB
  unsigned short* ldsA = smem;                    // [2][4096]
  unsigned short* ldsB = smem + 8192;             // [2][4096]
  int tid = threadIdx.x;
  int wave = tid >> 6, lane = tid & 63;

  // bijective chunked XCD swizzle
  int nwg = gridDim.x, orig = blockIdx.x;
  int q = nwg >> 3, r = nwg & 7;
  int xcd = orig & 7, lin = orig >> 3;
  int wgid = (xcd < r ? xcd * (q + 1) : r * (q + 1) + (xcd - r) * q) + lin;
  int mblk = wgid / 10, nblk = wgid - mblk * 10;
  int row0 = mblk * 128, col0 = nblk * 128;
  int wr = wave >> 1, wc = wave & 1, lcol = lane & 15;

  // staging: tile 8KB = 8 chunks of 1KB; wave stages chunks 2w,2w+1 of A and B
  const unsigned short* aSrc[2];
  const unsigned short* bSrc[2];
  int ldsOfs[2];
#pragma unroll
  for (int c2 = 0; c2 < 2; ++c2) {
    int off = (wave * 2 + c2) * 1024 + lane * 16;
    int rr = off >> 6;
    int lg8 = (((off >> 4) & 3) ^ ((rr >> 1) & 3)) * 8;   // inverse-swizzled src
    aSrc[c2] = Xbf + (size_t)(row0 + rr) * C + lg8;
    bSrc[c2] = WT2 + (size_t)(col0 + rr) * C + lg8;
    ldsOfs[c2] = (wave * 2 + c2) * 1024;
  }

  // ds_read byte offsets (swizzled)
  int aoff[4], boff[4];
  int kb = (lane >> 4) * 16;
#pragma unroll
  for (int i = 0; i < 4; ++i) {
    int ar = wr * 64 + i * 16 + lcol;
    aoff[i] = ar * 64 + (kb ^ (((ar >> 1) & 3) << 4));
    int bc = wc * 64 + i * 16 + lcol;
    boff[i] = bc * 64 + (kb ^ (((bc >> 1) & 3) << 4));
  }

  f32x4 acc[4][4];
#pragma unroll
  for (int i = 0; i < 4; ++i)
#pragma unroll
    for (int j = 0; j < 4; ++j) {
      f32x4 z; z[0] = 0.f; z[1] = 0.f; z[2] = 0.f; z[3] = 0.f;
      acc[i][j] = z;
    }

  auto stage = [&](int buf, int ks) {
    int kofs = ks * BK;
#pragma unroll
    for (int c2 = 0; c2 < 2; ++c2) {
      GLL16(aSrc[c2] + kofs, (char*)(ldsA + buf * 4096) + ldsOfs[c2]);
      GLL16(bSrc[c2] + kofs, (char*)(ldsB + buf * 4096) + ldsOfs[c2]);
    }
  };

  stage(0, 0);
  __syncthreads();

#pragma unroll
  for (int ks = 0; ks < 8; ++ks) {
    int cur = ks & 1;
    if (ks + 1 < 8) stage(cur ^ 1, ks + 1);
    bf16x8 af[4], bfr[4];
#pragma unroll
    for (int i = 0; i < 4; ++i) {
      af[i]  = *reinterpret_cast<const bf16x8*>((const char*)(ldsA + cur * 4096) + aoff[i]);
      bfr[i] = *reinterpret_cast<const bf16x8*>((const char*)(ldsB + cur * 4096) + boff[i]);
    }
#pragma unroll
    for (int mr = 0; mr < 4; ++mr)
#pragma unroll
      for (int nc = 0; nc < 4; ++nc)
        acc[mr][nc] = __builtin_amdgcn_mfma_f32_16x16x32_bf16(af[mr], bfr[nc], acc[mr][nc], 0, 0, 0);
    __syncthreads();
  }

  // epilogue: smem as logical [128][128] bf16 with granule rotation
  // phys granule p = ((c>>3) + r) & 15; entry = r*128 + p*8 + (c&7)
  int lrow4 = (lane >> 4) * 4;
#pragma unroll
  for (int mr = 0; mr < 4; ++mr)
#pragma unroll
    for (int nc = 0; nc < 4; ++nc)
#pragma unroll
      for (int reg = 0; reg < 4; ++reg) {
        int rr = wr * 64 + mr * 16 + lrow4 + reg;
        int cc = wc * 64 + nc * 16 + lcol;
        smem[rr * 128 + ((((cc >> 3) + rr) & 15) << 3) + (cc & 7)] =
            f2bf(acc[mr][nc][reg]);
      }
  __syncthreads();
#pragma unroll
  for (int rnd = 0; rnd < 8; ++rnd) {
    int rr = rnd * 16 + (tid >> 4);
    int g = tid & 15;
    int p = (g + rr) & 15;
    bf16x8 v = *reinterpret_cast<const bf16x8*>(smem + rr * 128 + p * 8);
    *reinterpret_cast<bf16x8*>(Y + (size_t)(row0 + rr) * NOUT + col0 + g * 8) = v;
  }
}

#define ACC(u, v)                                                            \
  do {                                                                       \
    float f0 = bf2f((v).x), f1 = bf2f((v).y), f2 = bf2f((v).z), f3 = bf2f((v).w); \
    switch ((u) >> 28) {                                                     \
      case 0: a0.x += f0; a0.y += f1; a0.z += f2; a0.w += f3; ++c0; break;   \
      case 1: a1.x += f0; a1.y += f1; a1.z += f2; a1.w += f3; ++c1; break;   \
      case 2: a2.x += f0; a2.y += f1; a2.z += f2; a2.w += f3; ++c2; break;   \
      default: a3.x += f0; a3.y += f1; a3.z += f2; a3.w += f3; ++c3; break;  \
    }                                                                        \
  } while (0)

// Fused gather+gate. One wave per dst: mean per-relation Y slices (+root+bias)
// -> u0; a = sigmoid(dot(u0,w1)+ax2+ab); out = tanh(u0)*a + X*(1-a).
__global__ void k_gg(const unsigned short* __restrict__ Y,
                     const unsigned int* __restrict__ sorted,
                     const int* __restrict__ rp, const float* __restrict__ X,
                     const float* __restrict__ bias, const float* __restrict__ attw,
                     const float* __restrict__ abp, const float* __restrict__ ax2,
                     float* __restrict__ out, int N) {
  int wave = threadIdx.x >> 6, lane = threadIdx.x & 63;
  int dst = blockIdx.x * 4 + wave;
  if (dst >= N) return;
  const us4* Yv = reinterpret_cast<const us4*>(Y);   // row stride 320 us4

  float4 a0 = make_float4(0, 0, 0, 0), a1 = a0, a2 = a0, a3 = a0;
  int c0 = 0, c1 = 0, c2 = 0, c3 = 0;
  int s = rp[dst], e2 = rp[dst + 1];

#define YIDX(u) ((size_t)((u) & 0x0FFFFFFFu) * 320 + (((u) >> 28) + 1) * 64 + lane)
  int e = s;
  for (; e + 8 <= e2; e += 8) {
    unsigned int u0 = sorted[e],     u1 = sorted[e + 1], u2 = sorted[e + 2], u3 = sorted[e + 3];
    unsigned int u4 = sorted[e + 4], u5 = sorted[e + 5], u6 = sorted[e + 6], u7 = sorted[e + 7];
    us4 v0 = Yv[YIDX(u0)], v1 = Yv[YIDX(u1)], v2 = Yv[YIDX(u2)], v3 = Yv[YIDX(u3)];
    us4 v4 = Yv[YIDX(u4)], v5 = Yv[YIDX(u5)], v6 = Yv[YIDX(u6)], v7 = Yv[YIDX(u7)];
    ACC(u0, v0); ACC(u1, v1); ACC(u2, v2); ACC(u3, v3);
    ACC(u4, v4); ACC(u5, v5); ACC(u6, v6); ACC(u7, v7);
  }
  for (; e + 4 <= e2; e += 4) {
    unsigned int u0 = sorted[e], u1 = sorted[e + 1], u2 = sorted[e + 2], u3 = sorted[e + 3];
    us4 v0 = Yv[YIDX(u0)], v1 = Yv[YIDX(u1)], v2 = Yv[YIDX(u2)], v3 = Yv[YIDX(u3)];
    ACC(u0, v0); ACC(u1, v1); ACC(u2, v2); ACC(u3, v3);
  }
  for (; e < e2; ++e) {
    unsigned int u = sorted[e];
    us4 v = Yv[YIDX(u)];
    ACC(u, v);
  }
#undef YIDX

  float s0 = 1.0f / (float)max(c0, 1);
  float s1 = 1.0f / (float)max(c1, 1);
  float s2 = 1.0f / (float)max(c2, 1);
  float s3 = 1.0f / (float)max(c3, 1);
  us4 rt = Yv[(size_t)dst * 320 + lane];              // root slice (m=0)
  float4 bi = reinterpret_cast<const float4*>(bias)[lane];
  float4 w1 = reinterpret_cast<const float4*>(attw)[lane];
  float4 u0;
  u0.x = a0.x * s0 + a1.x * s1 + a2.x * s2 + a3.x * s3 + bf2f(rt.x) + bi.x;
  u0.y = a0.y * s0 + a1.y * s1 + a2.y * s2 + a3.y * s3 + bf2f(rt.y) + bi.y;
  u0.z = a0.z * s0 + a1.z * s1 + a2.z * s2 + a3.z * s3 + bf2f(rt.z) + bi.z;
  u0.w = a0.w * s0 + a1.w * s1 + a2.w * s2 + a3.w * s3 + bf2f(rt.w) + bi.w;

  float p = u0.x * w1.x + u0.y * w1.y + u0.z * w1.z + u0.w * w1.w;
#pragma unroll
  for (int m2 = 32; m2 >= 1; m2 >>= 1) p += __shfl_xor(p, m2);
  float a = 1.0f / (1.0f + expf(-(p + ax2[dst] + abp[0])));
  float b = 1.0f - a;
  float4 x4 = reinterpret_cast<const float4*>(X + (size_t)dst * C)[lane];
  float4 h;
  h.x = tanhf(u0.x) * a + x4.x * b;
  h.y = tanhf(u0.y) * a + x4.y * b;
  h.z = tanhf(u0.z) * a + x4.z * b;
  h.w = tanhf(u0.w) * a + x4.w * b;
  reinterpret_cast<float4*>(out + (size_t)dst * C)[lane] = h;
}

extern "C" void kernel_launch(void* const* d_in, const int* in_sizes, int n_in,
                              void* d_out, int out_size, void* d_ws, size_t ws_size,
                              hipStream_t stream) {
  const float* X     = (const float*)d_in[0];
  const int*   eidx  = (const int*)d_in[1];
  const int*   etype = (const int*)d_in[2];
  const float* rel   = (const float*)d_in[3];
  const float* root  = (const float*)d_in[4];
  const float* bias  = (const float*)d_in[5];
  const float* attw  = (const float*)d_in[6];
  const float* ab    = (const float*)d_in[7];
  float* out = (float*)d_out;

  int N = in_sizes[0] / C;                // 50000
  int E = in_sizes[2];                    // 800000
  int rowsPad = ((N + 127) / 128) * 128;  // 50048
  const int* esrc = eidx;
  const int* edst = eidx + E;

  char* w = (char*)d_ws;
  size_t off = 0;
  auto alloc = [&](size_t bytes) -> void* {
    void* p = w + off;
    off += (bytes + 255) & ~(size_t)255;
    return p;
  };
  unsigned short* Y    = (unsigned short*)alloc((size_t)rowsPad * NOUT * 2);  // 128 MB
  unsigned short* Xbf  = (unsigned short*)alloc((size_t)rowsPad * C * 2);
  unsigned short* WT2  = (unsigned short*)alloc((size_t)NOUT * C * 2);
  float* ax2  = (float*)alloc((size_t)rowsPad * 4);
  int* cnt    = (int*)alloc((size_t)N * 4);
  int* rp     = (int*)alloc((size_t)(N + 1) * 4);
  int* cursor = (int*)alloc((size_t)N * 4);
  int* bsum   = (int*)alloc(1024);
  int* boffb  = (int*)alloc(1024);
  unsigned int* sorted = (unsigned int*)alloc((size_t)E * 4);

  int preBlocks = 80 + (rowsPad >> 2) + (N + 255) / 256;
  k_pre<<<preBlocks, 256, 0, stream>>>(X, rel, root, attw, Xbf, WT2, ax2, cnt, N, rowsPad);
  k_hist<<<(E + 255) / 256, 256, 0, stream>>>(edst, cnt, E);
  int NB = (N + 511) / 512;
  k_scan1<<<NB, 512, 0, stream>>>(cnt, rp, bsum, N);
  k_scan2<<<1, 64, 0, stream>>>(bsum, boffb, rp, NB, N);
  k_scan3<<<NB, 512, 0, stream>>>(rp, boffb, cursor, N);
  k_fill<<<(E + 255) / 256, 256, 0, stream>>>(esrc, edst, etype, cursor, sorted, E);
  k_gemm<<<(rowsPad / 128) * 10, 256, 0, stream>>>(Xbf, WT2, Y, rowsPad);
  k_gg<<<(N + 3) / 4, 256, 0, stream>>>(Y, sorted, rp, X, bias, attw, ab, ax2, out, N);
}

// Round 14
// 251.773 us; speedup vs baseline: 1.3826x; 1.0120x over previous
//
#include <hip/hip_runtime.h>
#include <hip/hip_bf16.h>

#define C 256
#define NOUT 1280
#define BK 32

typedef __attribute__((ext_vector_type(8))) short bf16x8;
typedef __attribute__((ext_vector_type(4))) float f32x4;
typedef __attribute__((ext_vector_type(4))) unsigned short us4;

#define GLL16(g, l)                                                         \
  __builtin_amdgcn_global_load_lds(                                         \
      (const __attribute__((address_space(1))) void*)(g),                   \
      (__attribute__((address_space(3))) void*)(l), 16, 0, 0)

__device__ __forceinline__ float bf2f(unsigned short u) {
  return __uint_as_float(((unsigned int)u) << 16);
}
__device__ __forceinline__ unsigned short f2bf(float f) {
  unsigned int x = __float_as_uint(f);
  unsigned int lsb = (x >> 16) & 1u;
  x += 0x7fffu + lsb;  // round-to-nearest-even
  return (unsigned short)(x >> 16);
}

// Fused prep.
// blocks [0,80): W transpose via LDS: WT2[n][k] = bf16(W_m[k][c]), n=m*256+c.
// [80, 80+rowsPad/4): X->bf16 rows + ax2[row] = dot(X,w2).  rest: cnt[0..4N) = 0.
__global__ void k_pre(const float* __restrict__ X, const float* __restrict__ rel,
                      const float* __restrict__ root, const float* __restrict__ attw,
                      unsigned short* __restrict__ Xbf, unsigned short* __restrict__ WT2,
                      float* __restrict__ ax2, int* __restrict__ cnt,
                      int N, int rowsPad) {
  __shared__ float tw[64][65];
  int b = blockIdx.x, t = threadIdx.x;
  if (b < 80) {
    int m = b >> 4, tile = b & 15;
    int ti = tile >> 2, tj = tile & 3;           // ti: k-tile, tj: c-tile
    const float* W = (m == 0) ? root : (rel + (size_t)(m - 1) * C * C);
    int row = t >> 2, cj = (t & 3) * 16;         // row = k within tile
    const float* src = W + (size_t)(ti * 64 + row) * C + tj * 64 + cj;
#pragma unroll
    for (int j = 0; j < 4; ++j) {
      float4 v = reinterpret_cast<const float4*>(src)[j];
      tw[row][cj + j * 4 + 0] = v.x;
      tw[row][cj + j * 4 + 1] = v.y;
      tw[row][cj + j * 4 + 2] = v.z;
      tw[row][cj + j * 4 + 3] = v.w;
    }
    __syncthreads();
    int c = t >> 2, k0 = (t & 3) * 16;           // c within tile
    int n = m * 256 + tj * 64 + c;
    unsigned short o[16];
#pragma unroll
    for (int k = 0; k < 16; ++k) o[k] = f2bf(tw[k0 + k][c]);
#pragma unroll
    for (int j = 0; j < 4; ++j)
      *reinterpret_cast<us4*>(WT2 + (size_t)n * C + ti * 64 + k0 + j * 4) =
          *reinterpret_cast<us4*>(&o[j * 4]);
  } else if (b < 80 + (rowsPad >> 2)) {
    int row = (b - 80) * 4 + (t >> 6);
    int lane = t & 63;
    if (row < N) {
      float4 v = reinterpret_cast<const float4*>(X + (size_t)row * C)[lane];
      float4 w2 = reinterpret_cast<const float4*>(attw + C)[lane];
      us4 o;
      o.x = f2bf(v.x); o.y = f2bf(v.y); o.z = f2bf(v.z); o.w = f2bf(v.w);
      reinterpret_cast<us4*>(Xbf)[(size_t)row * 64 + lane] = o;
      float p = v.x * w2.x + v.y * w2.y + v.z * w2.z + v.w * w2.w;
#pragma unroll
      for (int m2 = 32; m2 >= 1; m2 >>= 1) p += __shfl_xor(p, m2);
      if (lane == 0) ax2[row] = p;
    } else if (row < rowsPad) {
      us4 z; z.x = 0; z.y = 0; z.z = 0; z.w = 0;
      reinterpret_cast<us4*>(Xbf)[(size_t)row * 64 + lane] = z;
      if (lane == 0) ax2[row] = 0.f;
    }
  } else {
    int i = (b - 80 - (rowsPad >> 2)) * 256 + t;
    if (i < 4 * N) cnt[i] = 0;
  }
}

// histogram over (dst, relation) buckets
__global__ void k_hist(const int* __restrict__ edst, const int* __restrict__ etype,
                       int* __restrict__ cnt, int E) {
  int e = blockIdx.x * blockDim.x + threadIdx.x;
  if (e < E) atomicAdd(cnt + edst[e] * 4 + etype[e], 1);
}

__global__ void k_scan1(const int* __restrict__ cnt, int* __restrict__ rp,
                        int* __restrict__ bsum, int n) {
  __shared__ int s[512];
  int t = threadIdx.x;
  int i = blockIdx.x * 512 + t;
  int v = (i < n) ? cnt[i] : 0;
  s[t] = v;
  __syncthreads();
  for (int off = 1; off < 512; off <<= 1) {
    int add = (t >= off) ? s[t - off] : 0;
    __syncthreads();
    s[t] += add;
    __syncthreads();
  }
  if (i < n) rp[i] = s[t] - v;
  if (t == 511) bsum[blockIdx.x] = s[511];
}

__global__ void k_scan2(const int* __restrict__ bsum, int* __restrict__ boff,
                        int* __restrict__ rp, int nb, int n) {
  if (threadIdx.x == 0) {
    int run = 0;
    for (int b = 0; b < nb; ++b) { boff[b] = run; run += bsum[b]; }
    rp[n] = run;
  }
}

__global__ void k_scan3(int* __restrict__ rp, const int* __restrict__ boff,
                        int* __restrict__ cursor, int n) {
  int i = blockIdx.x * 512 + threadIdx.x;
  if (i < n) {
    int v = rp[i] + boff[blockIdx.x];
    rp[i] = v;
    cursor[i] = v;
  }
}

// bucket-fill by (dst,r); store the fully-encoded Y offset (us4 units):
// src*320 + (r+1)*64  ->  k_gg address is sorted[e] + lane.
__global__ void k_fill(const int* __restrict__ esrc, const int* __restrict__ edst,
                       const int* __restrict__ etype, int* __restrict__ cursor,
                       unsigned int* __restrict__ sorted, int E) {
  int e = blockIdx.x * blockDim.x + threadIdx.x;
  if (e >= E) return;
  int d = edst[e];
  int r = etype[e];
  int pos = atomicAdd(cursor + d * 4 + r, 1);
  sorted[pos] = (unsigned int)(esrc[e] * 320 + (r + 1) * 64);
}

// Y = Xbf @ WT2^T, M=rowsPad N=1280 K=256, Y bf16 [rowsPad][1280].
// 128x128 tile, 2-phase dbuf, GLL16 staging, 2-way-max XOR swizzle, XCD
// chunked swizzle, unrolled 8-step K loop, LDS-transposed coalesced epilogue.
__global__ __launch_bounds__(256) void k_gemm(
    const unsigned short* __restrict__ Xbf, const unsigned short* __restrict__ WT2,
    unsigned short* __restrict__ Y, int rowsPad) {
  __shared__ unsigned short smem[16384];          // 32KB
  unsigned short* ldsA = smem;                    // [2][4096]
  unsigned short* ldsB = smem + 8192;             // [2][4096]
  int tid = threadIdx.x;
  int wave = tid >> 6, lane = tid & 63;

  int nwg = gridDim.x, orig = blockIdx.x;
  int q = nwg >> 3, r = nwg & 7;
  int xcd = orig & 7, lin = orig >> 3;
  int wgid = (xcd < r ? xcd * (q + 1) : r * (q + 1) + (xcd - r) * q) + lin;
  int mblk = wgid / 10, nblk = wgid - mblk * 10;
  int row0 = mblk * 128, col0 = nblk * 128;
  int wr = wave >> 1, wc = wave & 1, lcol = lane & 15;

  const unsigned short* aSrc[2];
  const unsigned short* bSrc[2];
  int ldsOfs[2];
#pragma unroll
  for (int c2 = 0; c2 < 2; ++c2) {
    int off = (wave * 2 + c2) * 1024 + lane * 16;
    int rr = off >> 6;
    int lg8 = (((off >> 4) & 3) ^ ((rr >> 1) & 3)) * 8;
    aSrc[c2] = Xbf + (size_t)(row0 + rr) * C + lg8;
    bSrc[c2] = WT2 + (size_t)(col0 + rr) * C + lg8;
    ldsOfs[c2] = (wave * 2 + c2) * 1024;
  }

  int aoff[4], boff[4];
  int kb = (lane >> 4) * 16;
#pragma unroll
  for (int i = 0; i < 4; ++i) {
    int ar = wr * 64 + i * 16 + lcol;
    aoff[i] = ar * 64 + (kb ^ (((ar >> 1) & 3) << 4));
    int bc = wc * 64 + i * 16 + lcol;
    boff[i] = bc * 64 + (kb ^ (((bc >> 1) & 3) << 4));
  }

  f32x4 acc[4][4];
#pragma unroll
  for (int i = 0; i < 4; ++i)
#pragma unroll
    for (int j = 0; j < 4; ++j) {
      f32x4 z; z[0] = 0.f; z[1] = 0.f; z[2] = 0.f; z[3] = 0.f;
      acc[i][j] = z;
    }

  auto stage = [&](int buf, int ks) {
    int kofs = ks * BK;
#pragma unroll
    for (int c2 = 0; c2 < 2; ++c2) {
      GLL16(aSrc[c2] + kofs, (char*)(ldsA + buf * 4096) + ldsOfs[c2]);
      GLL16(bSrc[c2] + kofs, (char*)(ldsB + buf * 4096) + ldsOfs[c2]);
    }
  };

  stage(0, 0);
  __syncthreads();

#pragma unroll
  for (int ks = 0; ks < 8; ++ks) {
    int cur = ks & 1;
    if (ks + 1 < 8) stage(cur ^ 1, ks + 1);
    bf16x8 af[4], bfr[4];
#pragma unroll
    for (int i = 0; i < 4; ++i) {
      af[i]  = *reinterpret_cast<const bf16x8*>((const char*)(ldsA + cur * 4096) + aoff[i]);
      bfr[i] = *reinterpret_cast<const bf16x8*>((const char*)(ldsB + cur * 4096) + boff[i]);
    }
#pragma unroll
    for (int mr = 0; mr < 4; ++mr)
#pragma unroll
      for (int nc = 0; nc < 4; ++nc)
        acc[mr][nc] = __builtin_amdgcn_mfma_f32_16x16x32_bf16(af[mr], bfr[nc], acc[mr][nc], 0, 0, 0);
    __syncthreads();
  }

  int lrow4 = (lane >> 4) * 4;
#pragma unroll
  for (int mr = 0; mr < 4; ++mr)
#pragma unroll
    for (int nc = 0; nc < 4; ++nc)
#pragma unroll
      for (int reg = 0; reg < 4; ++reg) {
        int rr = wr * 64 + mr * 16 + lrow4 + reg;
        int cc = wc * 64 + nc * 16 + lcol;
        smem[rr * 128 + ((((cc >> 3) + rr) & 15) << 3) + (cc & 7)] =
            f2bf(acc[mr][nc][reg]);
      }
  __syncthreads();
#pragma unroll
  for (int rnd = 0; rnd < 8; ++rnd) {
    int rr = rnd * 16 + (tid >> 4);
    int g = tid & 15;
    int p = (g + rr) & 15;
    bf16x8 v = *reinterpret_cast<const bf16x8*>(smem + rr * 128 + p * 8);
    *reinterpret_cast<bf16x8*>(Y + (size_t)(row0 + rr) * NOUT + col0 + g * 8) = v;
  }
}

// Fused gather+gate, branch-free relation handling.
__device__ __forceinline__ float wsel(int e, int b1, int b2, int b3,
                                      float s0, float s1, float s2, float s3) {
  return e < b1 ? s0 : (e < b2 ? s1 : (e < b3 ? s2 : s3));
}

__global__ void k_gg(const unsigned short* __restrict__ Y,
                     const unsigned int* __restrict__ sorted,
                     const int* __restrict__ rp, const float* __restrict__ X,
                     const float* __restrict__ bias, const float* __restrict__ attw,
                     const float* __restrict__ abp, const float* __restrict__ ax2,
                     float* __restrict__ out, int N) {
  int wave = threadIdx.x >> 6, lane = threadIdx.x & 63;
  int dst = blockIdx.x * 4 + wave;
  if (dst >= N) return;
  const us4* Yv = reinterpret_cast<const us4*>(Y);   // row stride 320 us4

  int b0 = rp[dst * 4 + 0], b1 = rp[dst * 4 + 1], b2 = rp[dst * 4 + 2],
      b3 = rp[dst * 4 + 3], b4 = rp[dst * 4 + 4];
  float s0 = 1.0f / (float)max(b1 - b0, 1);
  float s1 = 1.0f / (float)max(b2 - b1, 1);
  float s2 = 1.0f / (float)max(b3 - b2, 1);
  float s3 = 1.0f / (float)max(b4 - b3, 1);

  float4 acc = make_float4(0.f, 0.f, 0.f, 0.f);

  auto gstep = [&](unsigned int u, float wt) {
    us4 v = Yv[(size_t)u + lane];
    acc.x += wt * bf2f(v.x);
    acc.y += wt * bf2f(v.y);
    acc.z += wt * bf2f(v.z);
    acc.w += wt * bf2f(v.w);
  };

  int e = b0;
  for (; e + 8 <= b4; e += 8) {
    unsigned int u0 = sorted[e],     u1 = sorted[e + 1], u2 = sorted[e + 2], u3 = sorted[e + 3];
    unsigned int u4 = sorted[e + 4], u5 = sorted[e + 5], u6 = sorted[e + 6], u7 = sorted[e + 7];
    float w0 = wsel(e + 0, b1, b2, b3, s0, s1, s2, s3);
    float w1 = wsel(e + 1, b1, b2, b3, s0, s1, s2, s3);
    float w2 = wsel(e + 2, b1, b2, b3, s0, s1, s2, s3);
    float w3 = wsel(e + 3, b1, b2, b3, s0, s1, s2, s3);
    float w4 = wsel(e + 4, b1, b2, b3, s0, s1, s2, s3);
    float w5 = wsel(e + 5, b1, b2, b3, s0, s1, s2, s3);
    float w6 = wsel(e + 6, b1, b2, b3, s0, s1, s2, s3);
    float w7 = wsel(e + 7, b1, b2, b3, s0, s1, s2, s3);
    gstep(u0, w0); gstep(u1, w1); gstep(u2, w2); gstep(u3, w3);
    gstep(u4, w4); gstep(u5, w5); gstep(u6, w6); gstep(u7, w7);
  }
  for (; e + 4 <= b4; e += 4) {
    unsigned int u0 = sorted[e], u1 = sorted[e + 1], u2 = sorted[e + 2], u3 = sorted[e + 3];
    float w0 = wsel(e + 0, b1, b2, b3, s0, s1, s2, s3);
    float w1 = wsel(e + 1, b1, b2, b3, s0, s1, s2, s3);
    float w2 = wsel(e + 2, b1, b2, b3, s0, s1, s2, s3);
    float w3 = wsel(e + 3, b1, b2, b3, s0, s1, s2, s3);
    gstep(u0, w0); gstep(u1, w1); gstep(u2, w2); gstep(u3, w3);
  }
  for (; e < b4; ++e) {
    gstep(sorted[e], wsel(e, b1, b2, b3, s0, s1, s2, s3));
  }

  us4 rt = Yv[(size_t)dst * 320 + lane];              // root slice (m=0)
  float4 bi = reinterpret_cast<const float4*>(bias)[lane];
  float4 w1v = reinterpret_cast<const float4*>(attw)[lane];
  float4 u0v;
  u0v.x = acc.x + bf2f(rt.x) + bi.x;
  u0v.y = acc.y + bf2f(rt.y) + bi.y;
  u0v.z = acc.z + bf2f(rt.z) + bi.z;
  u0v.w = acc.w + bf2f(rt.w) + bi.w;

  float p = u0v.x * w1v.x + u0v.y * w1v.y + u0v.z * w1v.z + u0v.w * w1v.w;
#pragma unroll
  for (int m2 = 32; m2 >= 1; m2 >>= 1) p += __shfl_xor(p, m2);
  float a = 1.0f / (1.0f + expf(-(p + ax2[dst] + abp[0])));
  float b = 1.0f - a;
  float4 x4 = reinterpret_cast<const float4*>(X + (size_t)dst * C)[lane];
  float4 h;
  h.x = tanhf(u0v.x) * a + x4.x * b;
  h.y = tanhf(u0v.y) * a + x4.y * b;
  h.z = tanhf(u0v.z) * a + x4.z * b;
  h.w = tanhf(u0v.w) * a + x4.w * b;
  reinterpret_cast<float4*>(out + (size_t)dst * C)[lane] = h;
}

extern "C" void kernel_launch(void* const* d_in, const int* in_sizes, int n_in,
                              void* d_out, int out_size, void* d_ws, size_t ws_size,
                              hipStream_t stream) {
  const float* X     = (const float*)d_in[0];
  const int*   eidx  = (const int*)d_in[1];
  const int*   etype = (const int*)d_in[2];
  const float* rel   = (const float*)d_in[3];
  const float* root  = (const float*)d_in[4];
  const float* bias  = (const float*)d_in[5];
  const float* attw  = (const float*)d_in[6];
  const float* ab    = (const float*)d_in[7];
  float* out = (float*)d_out;

  int N = in_sizes[0] / C;                // 50000
  int E = in_sizes[2];                    // 800000
  int rowsPad = ((N + 127) / 128) * 128;  // 50048
  const int* esrc = eidx;
  const int* edst = eidx + E;
  int n4 = 4 * N;                         // (dst, relation) bucket count

  char* w = (char*)d_ws;
  size_t off = 0;
  auto alloc = [&](size_t bytes) -> void* {
    void* p = w + off;
    off += (bytes + 255) & ~(size_t)255;
    return p;
  };
  unsigned short* Y    = (unsigned short*)alloc((size_t)rowsPad * NOUT * 2);  // 128 MB
  unsigned short* Xbf  = (unsigned short*)alloc((size_t)rowsPad * C * 2);
  unsigned short* WT2  = (unsigned short*)alloc((size_t)NOUT * C * 2);
  float* ax2  = (float*)alloc((size_t)rowsPad * 4);
  int* cnt    = (int*)alloc((size_t)n4 * 4);
  int* rp     = (int*)alloc((size_t)(n4 + 1) * 4);
  int* cursor = (int*)alloc((size_t)n4 * 4);
  int* bsum   = (int*)alloc(2048);
  int* boffb  = (int*)alloc(2048);
  unsigned int* sorted = (unsigned int*)alloc((size_t)E * 4);

  int preBlocks = 80 + (rowsPad >> 2) + (n4 + 255) / 256;
  k_pre<<<preBlocks, 256, 0, stream>>>(X, rel, root, attw, Xbf, WT2, ax2, cnt, N, rowsPad);
  k_hist<<<(E + 255) / 256, 256, 0, stream>>>(edst, etype, cnt, E);
  int NB = (n4 + 511) / 512;
  k_scan1<<<NB, 512, 0, stream>>>(cnt, rp, bsum, n4);
  k_scan2<<<1, 64, 0, stream>>>(bsum, boffb, rp, NB, n4);
  k_scan3<<<NB, 512, 0, stream>>>(rp, boffb, cursor, n4);
  k_fill<<<(E + 255) / 256, 256, 0, stream>>>(esrc, edst, etype, cursor, sorted, E);
  k_gemm<<<(rowsPad / 128) * 10, 256, 0, stream>>>(Xbf, WT2, Y, rowsPad);
  k_gg<<<(N + 3) / 4, 256, 0, stream>>>(Y, sorted, rp, X, bias, attw, ab, ax2, out, N);
}

// Round 15
// 250.310 us; speedup vs baseline: 1.3907x; 1.0058x over previous
//
#include <hip/hip_runtime.h>
#include <hip/hip_bf16.h>

#define C 256
#define NOUT 1280
#define BK 32

typedef __attribute__((ext_vector_type(8))) short bf16x8;
typedef __attribute__((ext_vector_type(4))) float f32x4;
typedef __attribute__((ext_vector_type(4))) unsigned short us4;

#define GLL16(g, l)                                                         \
  __builtin_amdgcn_global_load_lds(                                         \
      (const __attribute__((address_space(1))) void*)(g),                   \
      (__attribute__((address_space(3))) void*)(l), 16, 0, 0)

__device__ __forceinline__ float bf2f(unsigned short u) {
  return __uint_as_float(((unsigned int)u) << 16);
}
__device__ __forceinline__ unsigned short f2bf(float f) {
  unsigned int x = __float_as_uint(f);
  unsigned int lsb = (x >> 16) & 1u;
  x += 0x7fffu + lsb;  // round-to-nearest-even
  return (unsigned short)(x >> 16);
}

// Fused prep (cnt pre-zeroed by hipMemsetAsync).
// blocks [0,80): W transpose via LDS: WT2[n][k] = bf16(W_m[k][c]), n=m*256+c.
// [80, 80+rowsPad/4): X->bf16 rows + ax2[row] = dot(X,w2).
// rest: (dst,relation) histogram over edges.
__global__ void k_pre(const float* __restrict__ X, const float* __restrict__ rel,
                      const float* __restrict__ root, const float* __restrict__ attw,
                      const int* __restrict__ edst, const int* __restrict__ etype,
                      unsigned short* __restrict__ Xbf, unsigned short* __restrict__ WT2,
                      float* __restrict__ ax2, int* __restrict__ cnt,
                      int N, int rowsPad, int E) {
  __shared__ float tw[64][65];
  int b = blockIdx.x, t = threadIdx.x;
  if (b < 80) {
    int m = b >> 4, tile = b & 15;
    int ti = tile >> 2, tj = tile & 3;           // ti: k-tile, tj: c-tile
    const float* W = (m == 0) ? root : (rel + (size_t)(m - 1) * C * C);
    int row = t >> 2, cj = (t & 3) * 16;         // row = k within tile
    const float* src = W + (size_t)(ti * 64 + row) * C + tj * 64 + cj;
#pragma unroll
    for (int j = 0; j < 4; ++j) {
      float4 v = reinterpret_cast<const float4*>(src)[j];
      tw[row][cj + j * 4 + 0] = v.x;
      tw[row][cj + j * 4 + 1] = v.y;
      tw[row][cj + j * 4 + 2] = v.z;
      tw[row][cj + j * 4 + 3] = v.w;
    }
    __syncthreads();
    int c = t >> 2, k0 = (t & 3) * 16;           // c within tile
    int n = m * 256 + tj * 64 + c;
    unsigned short o[16];
#pragma unroll
    for (int k = 0; k < 16; ++k) o[k] = f2bf(tw[k0 + k][c]);
#pragma unroll
    for (int j = 0; j < 4; ++j)
      *reinterpret_cast<us4*>(WT2 + (size_t)n * C + ti * 64 + k0 + j * 4) =
          *reinterpret_cast<us4*>(&o[j * 4]);
  } else if (b < 80 + (rowsPad >> 2)) {
    int row = (b - 80) * 4 + (t >> 6);
    int lane = t & 63;
    if (row < N) {
      float4 v = reinterpret_cast<const float4*>(X + (size_t)row * C)[lane];
      float4 w2 = reinterpret_cast<const float4*>(attw + C)[lane];
      us4 o;
      o.x = f2bf(v.x); o.y = f2bf(v.y); o.z = f2bf(v.z); o.w = f2bf(v.w);
      reinterpret_cast<us4*>(Xbf)[(size_t)row * 64 + lane] = o;
      float p = v.x * w2.x + v.y * w2.y + v.z * w2.z + v.w * w2.w;
#pragma unroll
      for (int m2 = 32; m2 >= 1; m2 >>= 1) p += __shfl_xor(p, m2);
      if (lane == 0) ax2[row] = p;
    } else if (row < rowsPad) {
      us4 z; z.x = 0; z.y = 0; z.z = 0; z.w = 0;
      reinterpret_cast<us4*>(Xbf)[(size_t)row * 64 + lane] = z;
      if (lane == 0) ax2[row] = 0.f;
    }
  } else {
    int e = (b - 80 - (rowsPad >> 2)) * 256 + t;
    if (e < E) atomicAdd(cnt + edst[e] * 4 + etype[e], 1);
  }
}

__global__ void k_scan1(const int* __restrict__ cnt, int* __restrict__ rp,
                        int* __restrict__ bsum, int n) {
  __shared__ int s[512];
  int t = threadIdx.x;
  int i = blockIdx.x * 512 + t;
  int v = (i < n) ? cnt[i] : 0;
  s[t] = v;
  __syncthreads();
  for (int off = 1; off < 512; off <<= 1) {
    int add = (t >= off) ? s[t - off] : 0;
    __syncthreads();
    s[t] += add;
    __syncthreads();
  }
  if (i < n) rp[i] = s[t] - v;
  if (t == 511) bsum[blockIdx.x] = s[511];
}

__global__ void k_scan2(const int* __restrict__ bsum, int* __restrict__ boff,
                        int* __restrict__ rp, int nb, int n) {
  if (threadIdx.x == 0) {
    int run = 0;
    for (int b = 0; b < nb; ++b) { boff[b] = run; run += bsum[b]; }
    rp[n] = run;
  }
}

__global__ void k_scan3(int* __restrict__ rp, const int* __restrict__ boff,
                        int* __restrict__ cursor, int n) {
  int i = blockIdx.x * 512 + threadIdx.x;
  if (i < n) {
    int v = rp[i] + boff[blockIdx.x];
    rp[i] = v;
    cursor[i] = v;
  }
}

// bucket-fill by (dst,r); store the fully-encoded Y offset (us4 units):
// src*320 + (r+1)*64  ->  k_gg address is sorted[e] + lane.
__global__ void k_fill(const int* __restrict__ esrc, const int* __restrict__ edst,
                       const int* __restrict__ etype, int* __restrict__ cursor,
                       unsigned int* __restrict__ sorted, int E) {
  int e = blockIdx.x * blockDim.x + threadIdx.x;
  if (e >= E) return;
  int d = edst[e];
  int r = etype[e];
  int pos = atomicAdd(cursor + d * 4 + r, 1);
  sorted[pos] = (unsigned int)(esrc[e] * 320 + (r + 1) * 64);
}

// Y = Xbf @ WT2^T, M=rowsPad N=1280 K=256, Y bf16 [rowsPad][1280].
// 128x128 tile, 2-phase dbuf, GLL16 staging, 2-way-max XOR swizzle, XCD
// chunked swizzle, unrolled 8-step K loop, LDS-transposed coalesced epilogue.
__global__ __launch_bounds__(256) void k_gemm(
    const unsigned short* __restrict__ Xbf, const unsigned short* __restrict__ WT2,
    unsigned short* __restrict__ Y, int rowsPad) {
  __shared__ unsigned short smem[16384];          // 32KB
  unsigned short* ldsA = smem;                    // [2][4096]
  unsigned short* ldsB = smem + 8192;             // [2][4096]
  int tid = threadIdx.x;
  int wave = tid >> 6, lane = tid & 63;

  int nwg = gridDim.x, orig = blockIdx.x;
  int q = nwg >> 3, r = nwg & 7;
  int xcd = orig & 7, lin = orig >> 3;
  int wgid = (xcd < r ? xcd * (q + 1) : r * (q + 1) + (xcd - r) * q) + lin;
  int mblk = wgid / 10, nblk = wgid - mblk * 10;
  int row0 = mblk * 128, col0 = nblk * 128;
  int wr = wave >> 1, wc = wave & 1, lcol = lane & 15;

  const unsigned short* aSrc[2];
  const unsigned short* bSrc[2];
  int ldsOfs[2];
#pragma unroll
  for (int c2 = 0; c2 < 2; ++c2) {
    int off = (wave * 2 + c2) * 1024 + lane * 16;
    int rr = off >> 6;
    int lg8 = (((off >> 4) & 3) ^ ((rr >> 1) & 3)) * 8;
    aSrc[c2] = Xbf + (size_t)(row0 + rr) * C + lg8;
    bSrc[c2] = WT2 + (size_t)(col0 + rr) * C + lg8;
    ldsOfs[c2] = (wave * 2 + c2) * 1024;
  }

  int aoff[4], boff[4];
  int kb = (lane >> 4) * 16;
#pragma unroll
  for (int i = 0; i < 4; ++i) {
    int ar = wr * 64 + i * 16 + lcol;
    aoff[i] = ar * 64 + (kb ^ (((ar >> 1) & 3) << 4));
    int bc = wc * 64 + i * 16 + lcol;
    boff[i] = bc * 64 + (kb ^ (((bc >> 1) & 3) << 4));
  }

  f32x4 acc[4][4];
#pragma unroll
  for (int i = 0; i < 4; ++i)
#pragma unroll
    for (int j = 0; j < 4; ++j) {
      f32x4 z; z[0] = 0.f; z[1] = 0.f; z[2] = 0.f; z[3] = 0.f;
      acc[i][j] = z;
    }

  auto stage = [&](int buf, int ks) {
    int kofs = ks * BK;
#pragma unroll
    for (int c2 = 0; c2 < 2; ++c2) {
      GLL16(aSrc[c2] + kofs, (char*)(ldsA + buf * 4096) + ldsOfs[c2]);
      GLL16(bSrc[c2] + kofs, (char*)(ldsB + buf * 4096) + ldsOfs[c2]);
    }
  };

  stage(0, 0);
  __syncthreads();

#pragma unroll
  for (int ks = 0; ks < 8; ++ks) {
    int cur = ks & 1;
    if (ks + 1 < 8) stage(cur ^ 1, ks + 1);
    bf16x8 af[4], bfr[4];
#pragma unroll
    for (int i = 0; i < 4; ++i) {
      af[i]  = *reinterpret_cast<const bf16x8*>((const char*)(ldsA + cur * 4096) + aoff[i]);
      bfr[i] = *reinterpret_cast<const bf16x8*>((const char*)(ldsB + cur * 4096) + boff[i]);
    }
#pragma unroll
    for (int mr = 0; mr < 4; ++mr)
#pragma unroll
      for (int nc = 0; nc < 4; ++nc)
        acc[mr][nc] = __builtin_amdgcn_mfma_f32_16x16x32_bf16(af[mr], bfr[nc], acc[mr][nc], 0, 0, 0);
    __syncthreads();
  }

  int lrow4 = (lane >> 4) * 4;
#pragma unroll
  for (int mr = 0; mr < 4; ++mr)
#pragma unroll
    for (int nc = 0; nc < 4; ++nc)
#pragma unroll
      for (int reg = 0; reg < 4; ++reg) {
        int rr = wr * 64 + mr * 16 + lrow4 + reg;
        int cc = wc * 64 + nc * 16 + lcol;
        smem[rr * 128 + ((((cc >> 3) + rr) & 15) << 3) + (cc & 7)] =
            f2bf(acc[mr][nc][reg]);
      }
  __syncthreads();
#pragma unroll
  for (int rnd = 0; rnd < 8; ++rnd) {
    int rr = rnd * 16 + (tid >> 4);
    int g = tid & 15;
    int p = (g + rr) & 15;
    bf16x8 v = *reinterpret_cast<const bf16x8*>(smem + rr * 128 + p * 8);
    *reinterpret_cast<bf16x8*>(Y + (size_t)(row0 + rr) * NOUT + col0 + g * 8) = v;
  }
}

// Fused gather+gate, branch-free, split-phase unroll-8 (loads fully in
// flight before consume; launch_bounds(256,4) lifts the VGPR cap so the
// 8 Y-rows coexist in registers).
__device__ __forceinline__ float wsel(int e, int b1, int b2, int b3,
                                      float s0, float s1, float s2, float s3) {
  return e < b1 ? s0 : (e < b2 ? s1 : (e < b3 ? s2 : s3));
}

__global__ __launch_bounds__(256, 4) void k_gg(
    const unsigned short* __restrict__ Y, const unsigned int* __restrict__ sorted,
    const int* __restrict__ rp, const float* __restrict__ X,
    const float* __restrict__ bias, const float* __restrict__ attw,
    const float* __restrict__ abp, const float* __restrict__ ax2,
    float* __restrict__ out, int N) {
  int wave = threadIdx.x >> 6, lane = threadIdx.x & 63;
  int dst = blockIdx.x * 4 + wave;
  if (dst >= N) return;
  const us4* Yv = reinterpret_cast<const us4*>(Y);   // row stride 320 us4

  // issue independent far loads early (T14): consumed after the edge loop
  us4 rt = Yv[(size_t)dst * 320 + lane];              // root slice (m=0)
  float4 x4 = reinterpret_cast<const float4*>(X + (size_t)dst * C)[lane];
  float4 bi = reinterpret_cast<const float4*>(bias)[lane];
  float4 w1v = reinterpret_cast<const float4*>(attw)[lane];
  float axv = ax2[dst];

  int b0 = rp[dst * 4 + 0], b1 = rp[dst * 4 + 1], b2 = rp[dst * 4 + 2],
      b3 = rp[dst * 4 + 3], b4 = rp[dst * 4 + 4];
  float s0 = 1.0f / (float)max(b1 - b0, 1);
  float s1 = 1.0f / (float)max(b2 - b1, 1);
  float s2 = 1.0f / (float)max(b3 - b2, 1);
  float s3 = 1.0f / (float)max(b4 - b3, 1);

  float4 acc = make_float4(0.f, 0.f, 0.f, 0.f);

  int e = b0;
  for (; e + 8 <= b4; e += 8) {
    unsigned int u0 = sorted[e],     u1 = sorted[e + 1], u2 = sorted[e + 2], u3 = sorted[e + 3];
    unsigned int u4 = sorted[e + 4], u5 = sorted[e + 5], u6 = sorted[e + 6], u7 = sorted[e + 7];
    // phase 1: issue all 8 row loads
    us4 v0 = Yv[(size_t)u0 + lane];
    us4 v1 = Yv[(size_t)u1 + lane];
    us4 v2 = Yv[(size_t)u2 + lane];
    us4 v3 = Yv[(size_t)u3 + lane];
    us4 v4 = Yv[(size_t)u4 + lane];
    us4 v5 = Yv[(size_t)u5 + lane];
    us4 v6 = Yv[(size_t)u6 + lane];
    us4 v7 = Yv[(size_t)u7 + lane];
    // phase 2: weights (VALU only)
    float w0 = wsel(e + 0, b1, b2, b3, s0, s1, s2, s3);
    float w1 = wsel(e + 1, b1, b2, b3, s0, s1, s2, s3);
    float w2 = wsel(e + 2, b1, b2, b3, s0, s1, s2, s3);
    float w3 = wsel(e + 3, b1, b2, b3, s0, s1, s2, s3);
    float w4 = wsel(e + 4, b1, b2, b3, s0, s1, s2, s3);
    float w5 = wsel(e + 5, b1, b2, b3, s0, s1, s2, s3);
    float w6 = wsel(e + 6, b1, b2, b3, s0, s1, s2, s3);
    float w7 = wsel(e + 7, b1, b2, b3, s0, s1, s2, s3);
    // phase 3: consume
    acc.x += w0 * bf2f(v0.x); acc.y += w0 * bf2f(v0.y); acc.z += w0 * bf2f(v0.z); acc.w += w0 * bf2f(v0.w);
    acc.x += w1 * bf2f(v1.x); acc.y += w1 * bf2f(v1.y); acc.z += w1 * bf2f(v1.z); acc.w += w1 * bf2f(v1.w);
    acc.x += w2 * bf2f(v2.x); acc.y += w2 * bf2f(v2.y); acc.z += w2 * bf2f(v2.z); acc.w += w2 * bf2f(v2.w);
    acc.x += w3 * bf2f(v3.x); acc.y += w3 * bf2f(v3.y); acc.z += w3 * bf2f(v3.z); acc.w += w3 * bf2f(v3.w);
    acc.x += w4 * bf2f(v4.x); acc.y += w4 * bf2f(v4.y); acc.z += w4 * bf2f(v4.z); acc.w += w4 * bf2f(v4.w);
    acc.x += w5 * bf2f(v5.x); acc.y += w5 * bf2f(v5.y); acc.z += w5 * bf2f(v5.z); acc.w += w5 * bf2f(v5.w);
    acc.x += w6 * bf2f(v6.x); acc.y += w6 * bf2f(v6.y); acc.z += w6 * bf2f(v6.z); acc.w += w6 * bf2f(v6.w);
    acc.x += w7 * bf2f(v7.x); acc.y += w7 * bf2f(v7.y); acc.z += w7 * bf2f(v7.z); acc.w += w7 * bf2f(v7.w);
  }
  for (; e + 4 <= b4; e += 4) {
    unsigned int u0 = sorted[e], u1 = sorted[e + 1], u2 = sorted[e + 2], u3 = sorted[e + 3];
    us4 v0 = Yv[(size_t)u0 + lane];
    us4 v1 = Yv[(size_t)u1 + lane];
    us4 v2 = Yv[(size_t)u2 + lane];
    us4 v3 = Yv[(size_t)u3 + lane];
    float w0 = wsel(e + 0, b1, b2, b3, s0, s1, s2, s3);
    float w1 = wsel(e + 1, b1, b2, b3, s0, s1, s2, s3);
    float w2 = wsel(e + 2, b1, b2, b3, s0, s1, s2, s3);
    float w3 = wsel(e + 3, b1, b2, b3, s0, s1, s2, s3);
    acc.x += w0 * bf2f(v0.x); acc.y += w0 * bf2f(v0.y); acc.z += w0 * bf2f(v0.z); acc.w += w0 * bf2f(v0.w);
    acc.x += w1 * bf2f(v1.x); acc.y += w1 * bf2f(v1.y); acc.z += w1 * bf2f(v1.z); acc.w += w1 * bf2f(v1.w);
    acc.x += w2 * bf2f(v2.x); acc.y += w2 * bf2f(v2.y); acc.z += w2 * bf2f(v2.z); acc.w += w2 * bf2f(v2.w);
    acc.x += w3 * bf2f(v3.x); acc.y += w3 * bf2f(v3.y); acc.z += w3 * bf2f(v3.z); acc.w += w3 * bf2f(v3.w);
  }
  for (; e < b4; ++e) {
    unsigned int u = sorted[e];
    float wt = wsel(e, b1, b2, b3, s0, s1, s2, s3);
    us4 v = Yv[(size_t)u + lane];
    acc.x += wt * bf2f(v.x); acc.y += wt * bf2f(v.y);
    acc.z += wt * bf2f(v.z); acc.w += wt * bf2f(v.w);
  }

  float4 u0v;
  u0v.x = acc.x + bf2f(rt.x) + bi.x;
  u0v.y = acc.y + bf2f(rt.y) + bi.y;
  u0v.z = acc.z + bf2f(rt.z) + bi.z;
  u0v.w = acc.w + bf2f(rt.w) + bi.w;

  float p = u0v.x * w1v.x + u0v.y * w1v.y + u0v.z * w1v.z + u0v.w * w1v.w;
#pragma unroll
  for (int m2 = 32; m2 >= 1; m2 >>= 1) p += __shfl_xor(p, m2);
  float a = 1.0f / (1.0f + expf(-(p + axv + abp[0])));
  float b = 1.0f - a;
  float4 h;
  h.x = tanhf(u0v.x) * a + x4.x * b;
  h.y = tanhf(u0v.y) * a + x4.y * b;
  h.z = tanhf(u0v.z) * a + x4.z * b;
  h.w = tanhf(u0v.w) * a + x4.w * b;
  reinterpret_cast<float4*>(out + (size_t)dst * C)[lane] = h;
}

extern "C" void kernel_launch(void* const* d_in, const int* in_sizes, int n_in,
                              void* d_out, int out_size, void* d_ws, size_t ws_size,
                              hipStream_t stream) {
  const float* X     = (const float*)d_in[0];
  const int*   eidx  = (const int*)d_in[1];
  const int*   etype = (const int*)d_in[2];
  const float* rel   = (const float*)d_in[3];
  const float* root  = (const float*)d_in[4];
  const float* bias  = (const float*)d_in[5];
  const float* attw  = (const float*)d_in[6];
  const float* ab    = (const float*)d_in[7];
  float* out = (float*)d_out;

  int N = in_sizes[0] / C;                // 50000
  int E = in_sizes[2];                    // 800000
  int rowsPad = ((N + 127) / 128) * 128;  // 50048
  const int* esrc = eidx;
  const int* edst = eidx + E;
  int n4 = 4 * N;                         // (dst, relation) bucket count

  char* w = (char*)d_ws;
  size_t off = 0;
  auto alloc = [&](size_t bytes) -> void* {
    void* p = w + off;
    off += (bytes + 255) & ~(size_t)255;
    return p;
  };
  unsigned short* Y    = (unsigned short*)alloc((size_t)rowsPad * NOUT * 2);  // 128 MB
  unsigned short* Xbf  = (unsigned short*)alloc((size_t)rowsPad * C * 2);
  unsigned short* WT2  = (unsigned short*)alloc((size_t)NOUT * C * 2);
  float* ax2  = (float*)alloc((size_t)rowsPad * 4);
  int* cnt    = (int*)alloc((size_t)n4 * 4);
  int* rp     = (int*)alloc((size_t)(n4 + 1) * 4);
  int* cursor = (int*)alloc((size_t)n4 * 4);
  int* bsum   = (int*)alloc(2048);
  int* boffb  = (int*)alloc(2048);
  unsigned int* sorted = (unsigned int*)alloc((size_t)E * 4);

  hipMemsetAsync(cnt, 0, (size_t)n4 * 4, stream);
  int preBlocks = 80 + (rowsPad >> 2) + (E + 255) / 256;
  k_pre<<<preBlocks, 256, 0, stream>>>(X, rel, root, attw, edst, etype,
                                       Xbf, WT2, ax2, cnt, N, rowsPad, E);
  int NB = (n4 + 511) / 512;
  k_scan1<<<NB, 512, 0, stream>>>(cnt, rp, bsum, n4);
  k_scan2<<<1, 64, 0, stream>>>(bsum, boffb, rp, NB, n4);
  k_scan3<<<NB, 512, 0, stream>>>(rp, boffb, cursor, n4);
  k_fill<<<(E + 255) / 256, 256, 0, stream>>>(esrc, edst, etype, cursor, sorted, E);
  k_gemm<<<(rowsPad / 128) * 10, 256, 0, stream>>>(Xbf, WT2, Y, rowsPad);
  k_gg<<<(N + 3) / 4, 256, 0, stream>>>(Y, sorted, rp, X, bias, attw, ab, ax2, out, N);
}

// Round 16
// 221.848 us; speedup vs baseline: 1.5691x; 1.1283x over previous
//
#include <hip/hip_runtime.h>
#include <hip/hip_bf16.h>

#define C 256
#define NOUT 1280
#define BK 32

typedef __attribute__((ext_vector_type(8))) short bf16x8;
typedef __attribute__((ext_vector_type(4))) float f32x4;
typedef __attribute__((ext_vector_type(4))) unsigned short us4;

#define GLL16(g, l)                                                         \
  __builtin_amdgcn_global_load_lds(                                         \
      (const __attribute__((address_space(1))) void*)(g),                   \
      (__attribute__((address_space(3))) void*)(l), 16, 0, 0)

__device__ __forceinline__ float bf2f(unsigned short u) {
  return __uint_as_float(((unsigned int)u) << 16);
}
__device__ __forceinline__ unsigned short f2bf(float f) {
  unsigned int x = __float_as_uint(f);
  unsigned int lsb = (x >> 16) & 1u;
  x += 0x7fffu + lsb;  // round-to-nearest-even
  return (unsigned short)(x >> 16);
}

// Fused prep (cnt pre-zeroed by hipMemsetAsync).
// blocks [0,80): W transpose via LDS: WT2[n][k] = bf16(W_m[k][c]), n=m*256+c.
// [80, 80+rowsPad/4): X->bf16 rows + ax2[row] = dot(X,w2).
// rest: (dst,relation) histogram; the returned old value IS the edge's
// within-bucket rank -> stored for the atomic-free fill.
__global__ void k_pre(const float* __restrict__ X, const float* __restrict__ rel,
                      const float* __restrict__ root, const float* __restrict__ attw,
                      const int* __restrict__ edst, const int* __restrict__ etype,
                      unsigned short* __restrict__ Xbf, unsigned short* __restrict__ WT2,
                      float* __restrict__ ax2, int* __restrict__ cnt,
                      int* __restrict__ rank, int N, int rowsPad, int E) {
  __shared__ float tw[64][65];
  int b = blockIdx.x, t = threadIdx.x;
  if (b < 80) {
    int m = b >> 4, tile = b & 15;
    int ti = tile >> 2, tj = tile & 3;           // ti: k-tile, tj: c-tile
    const float* W = (m == 0) ? root : (rel + (size_t)(m - 1) * C * C);
    int row = t >> 2, cj = (t & 3) * 16;         // row = k within tile
    const float* src = W + (size_t)(ti * 64 + row) * C + tj * 64 + cj;
#pragma unroll
    for (int j = 0; j < 4; ++j) {
      float4 v = reinterpret_cast<const float4*>(src)[j];
      tw[row][cj + j * 4 + 0] = v.x;
      tw[row][cj + j * 4 + 1] = v.y;
      tw[row][cj + j * 4 + 2] = v.z;
      tw[row][cj + j * 4 + 3] = v.w;
    }
    __syncthreads();
    int c = t >> 2, k0 = (t & 3) * 16;           // c within tile
    int n = m * 256 + tj * 64 + c;
    unsigned short o[16];
#pragma unroll
    for (int k = 0; k < 16; ++k) o[k] = f2bf(tw[k0 + k][c]);
#pragma unroll
    for (int j = 0; j < 4; ++j)
      *reinterpret_cast<us4*>(WT2 + (size_t)n * C + ti * 64 + k0 + j * 4) =
          *reinterpret_cast<us4*>(&o[j * 4]);
  } else if (b < 80 + (rowsPad >> 2)) {
    int row = (b - 80) * 4 + (t >> 6);
    int lane = t & 63;
    if (row < N) {
      float4 v = reinterpret_cast<const float4*>(X + (size_t)row * C)[lane];
      float4 w2 = reinterpret_cast<const float4*>(attw + C)[lane];
      us4 o;
      o.x = f2bf(v.x); o.y = f2bf(v.y); o.z = f2bf(v.z); o.w = f2bf(v.w);
      reinterpret_cast<us4*>(Xbf)[(size_t)row * 64 + lane] = o;
      float p = v.x * w2.x + v.y * w2.y + v.z * w2.z + v.w * w2.w;
#pragma unroll
      for (int m2 = 32; m2 >= 1; m2 >>= 1) p += __shfl_xor(p, m2);
      if (lane == 0) ax2[row] = p;
    } else if (row < rowsPad) {
      us4 z; z.x = 0; z.y = 0; z.z = 0; z.w = 0;
      reinterpret_cast<us4*>(Xbf)[(size_t)row * 64 + lane] = z;
      if (lane == 0) ax2[row] = 0.f;
    }
  } else {
    int e = (b - 80 - (rowsPad >> 2)) * 256 + t;
    if (e < E) rank[e] = atomicAdd(cnt + edst[e] * 4 + etype[e], 1);
  }
}

__global__ void k_scan1(const int* __restrict__ cnt, int* __restrict__ rp,
                        int* __restrict__ bsum, int n) {
  __shared__ int s[512];
  int t = threadIdx.x;
  int i = blockIdx.x * 512 + t;
  int v = (i < n) ? cnt[i] : 0;
  s[t] = v;
  __syncthreads();
  for (int off = 1; off < 512; off <<= 1) {
    int add = (t >= off) ? s[t - off] : 0;
    __syncthreads();
    s[t] += add;
    __syncthreads();
  }
  if (i < n) rp[i] = s[t] - v;
  if (t == 511) bsum[blockIdx.x] = s[511];
}

__global__ void k_scan2(const int* __restrict__ bsum, int* __restrict__ boff,
                        int* __restrict__ rp, int nb, int n) {
  if (threadIdx.x == 0) {
    int run = 0;
    for (int b = 0; b < nb; ++b) { boff[b] = run; run += bsum[b]; }
    rp[n] = run;
  }
}

__global__ void k_scan3(int* __restrict__ rp, const int* __restrict__ boff, int n) {
  int i = blockIdx.x * 512 + threadIdx.x;
  if (i < n) rp[i] += boff[blockIdx.x];
}

// Atomic-free fill: pos = rp[bucket] + rank[e] (unique within bucket).
// Stores the fully-encoded Y offset (us4 units): src*320 + (r+1)*64.
__global__ void k_fill(const int* __restrict__ esrc, const int* __restrict__ edst,
                       const int* __restrict__ etype, const int* __restrict__ rank,
                       const int* __restrict__ rp, unsigned int* __restrict__ sorted,
                       int E) {
  int e = blockIdx.x * blockDim.x + threadIdx.x;
  if (e >= E) return;
  int d = edst[e];
  int r = etype[e];
  int pos = rp[d * 4 + r] + rank[e];
  sorted[pos] = (unsigned int)(esrc[e] * 320 + (r + 1) * 64);
}

// Y = Xbf @ WT2^T, M=rowsPad N=1280 K=256, Y bf16 [rowsPad][1280].
// 128x128 tile, 2-phase dbuf, GLL16 staging, 2-way-max XOR swizzle, XCD
// chunked swizzle, unrolled 8-step K loop, LDS-transposed coalesced epilogue.
__global__ __launch_bounds__(256) void k_gemm(
    const unsigned short* __restrict__ Xbf, const unsigned short* __restrict__ WT2,
    unsigned short* __restrict__ Y, int rowsPad) {
  __shared__ unsigned short smem[16384];          // 32KB
  unsigned short* ldsA = smem;                    // [2][4096]
  unsigned short* ldsB = smem + 8192;             // [2][4096]
  int tid = threadIdx.x;
  int wave = tid >> 6, lane = tid & 63;

  int nwg = gridDim.x, orig = blockIdx.x;
  int q = nwg >> 3, r = nwg & 7;
  int xcd = orig & 7, lin = orig >> 3;
  int wgid = (xcd < r ? xcd * (q + 1) : r * (q + 1) + (xcd - r) * q) + lin;
  int mblk = wgid / 10, nblk = wgid - mblk * 10;
  int row0 = mblk * 128, col0 = nblk * 128;
  int wr = wave >> 1, wc = wave & 1, lcol = lane & 15;

  const unsigned short* aSrc[2];
  const unsigned short* bSrc[2];
  int ldsOfs[2];
#pragma unroll
  for (int c2 = 0; c2 < 2; ++c2) {
    int off = (wave * 2 + c2) * 1024 + lane * 16;
    int rr = off >> 6;
    int lg8 = (((off >> 4) & 3) ^ ((rr >> 1) & 3)) * 8;
    aSrc[c2] = Xbf + (size_t)(row0 + rr) * C + lg8;
    bSrc[c2] = WT2 + (size_t)(col0 + rr) * C + lg8;
    ldsOfs[c2] = (wave * 2 + c2) * 1024;
  }

  int aoff[4], boff[4];
  int kb = (lane >> 4) * 16;
#pragma unroll
  for (int i = 0; i < 4; ++i) {
    int ar = wr * 64 + i * 16 + lcol;
    aoff[i] = ar * 64 + (kb ^ (((ar >> 1) & 3) << 4));
    int bc = wc * 64 + i * 16 + lcol;
    boff[i] = bc * 64 + (kb ^ (((bc >> 1) & 3) << 4));
  }

  f32x4 acc[4][4];
#pragma unroll
  for (int i = 0; i < 4; ++i)
#pragma unroll
    for (int j = 0; j < 4; ++j) {
      f32x4 z; z[0] = 0.f; z[1] = 0.f; z[2] = 0.f; z[3] = 0.f;
      acc[i][j] = z;
    }

  auto stage = [&](int buf, int ks) {
    int kofs = ks * BK;
#pragma unroll
    for (int c2 = 0; c2 < 2; ++c2) {
      GLL16(aSrc[c2] + kofs, (char*)(ldsA + buf * 4096) + ldsOfs[c2]);
      GLL16(bSrc[c2] + kofs, (char*)(ldsB + buf * 4096) + ldsOfs[c2]);
    }
  };

  stage(0, 0);
  __syncthreads();

#pragma unroll
  for (int ks = 0; ks < 8; ++ks) {
    int cur = ks & 1;
    if (ks + 1 < 8) stage(cur ^ 1, ks + 1);
    bf16x8 af[4], bfr[4];
#pragma unroll
    for (int i = 0; i < 4; ++i) {
      af[i]  = *reinterpret_cast<const bf16x8*>((const char*)(ldsA + cur * 4096) + aoff[i]);
      bfr[i] = *reinterpret_cast<const bf16x8*>((const char*)(ldsB + cur * 4096) + boff[i]);
    }
#pragma unroll
    for (int mr = 0; mr < 4; ++mr)
#pragma unroll
      for (int nc = 0; nc < 4; ++nc)
        acc[mr][nc] = __builtin_amdgcn_mfma_f32_16x16x32_bf16(af[mr], bfr[nc], acc[mr][nc], 0, 0, 0);
    __syncthreads();
  }

  int lrow4 = (lane >> 4) * 4;
#pragma unroll
  for (int mr = 0; mr < 4; ++mr)
#pragma unroll
    for (int nc = 0; nc < 4; ++nc)
#pragma unroll
      for (int reg = 0; reg < 4; ++reg) {
        int rr = wr * 64 + mr * 16 + lrow4 + reg;
        int cc = wc * 64 + nc * 16 + lcol;
        smem[rr * 128 + ((((cc >> 3) + rr) & 15) << 3) + (cc & 7)] =
            f2bf(acc[mr][nc][reg]);
      }
  __syncthreads();
#pragma unroll
  for (int rnd = 0; rnd < 8; ++rnd) {
    int rr = rnd * 16 + (tid >> 4);
    int g = tid & 15;
    int p = (g + rr) & 15;
    bf16x8 v = *reinterpret_cast<const bf16x8*>(smem + rr * 128 + p * 8);
    *reinterpret_cast<bf16x8*>(Y + (size_t)(row0 + rr) * NOUT + col0 + g * 8) = v;
  }
}

// Fused gather+gate, branch-free. Blend input read from Xbf (25.6MB bf16)
// instead of X fp32 -> less FETCH and less L3 pollution of Y.
__device__ __forceinline__ float wsel(int e, int b1, int b2, int b3,
                                      float s0, float s1, float s2, float s3) {
  return e < b1 ? s0 : (e < b2 ? s1 : (e < b3 ? s2 : s3));
}

__global__ __launch_bounds__(256, 4) void k_gg(
    const unsigned short* __restrict__ Y, const unsigned int* __restrict__ sorted,
    const int* __restrict__ rp, const unsigned short* __restrict__ Xbf,
    const float* __restrict__ bias, const float* __restrict__ attw,
    const float* __restrict__ abp, const float* __restrict__ ax2,
    float* __restrict__ out, int N) {
  int wave = threadIdx.x >> 6, lane = threadIdx.x & 63;
  int dst = blockIdx.x * 4 + wave;
  if (dst >= N) return;
  const us4* Yv = reinterpret_cast<const us4*>(Y);   // row stride 320 us4

  // independent far loads issued early
  us4 rt = Yv[(size_t)dst * 320 + lane];              // root slice (m=0)
  us4 xb = reinterpret_cast<const us4*>(Xbf)[(size_t)dst * 64 + lane];
  float4 bi = reinterpret_cast<const float4*>(bias)[lane];
  float4 w1v = reinterpret_cast<const float4*>(attw)[lane];
  float axv = ax2[dst];

  int b0 = rp[dst * 4 + 0], b1 = rp[dst * 4 + 1], b2 = rp[dst * 4 + 2],
      b3 = rp[dst * 4 + 3], b4 = rp[dst * 4 + 4];
  float s0 = 1.0f / (float)max(b1 - b0, 1);
  float s1 = 1.0f / (float)max(b2 - b1, 1);
  float s2 = 1.0f / (float)max(b3 - b2, 1);
  float s3 = 1.0f / (float)max(b4 - b3, 1);

  float4 acc = make_float4(0.f, 0.f, 0.f, 0.f);

  auto consume = [&](const us4& v, float wt) {
    acc.x += wt * bf2f(v.x);
    acc.y += wt * bf2f(v.y);
    acc.z += wt * bf2f(v.z);
    acc.w += wt * bf2f(v.w);
  };

  int e = b0;
  for (; e + 8 <= b4; e += 8) {
    unsigned int u0 = sorted[e],     u1 = sorted[e + 1], u2 = sorted[e + 2], u3 = sorted[e + 3];
    unsigned int u4 = sorted[e + 4], u5 = sorted[e + 5], u6 = sorted[e + 6], u7 = sorted[e + 7];
    us4 v0 = Yv[(size_t)u0 + lane];
    us4 v1 = Yv[(size_t)u1 + lane];
    us4 v2 = Yv[(size_t)u2 + lane];
    us4 v3 = Yv[(size_t)u3 + lane];
    us4 v4 = Yv[(size_t)u4 + lane];
    us4 v5 = Yv[(size_t)u5 + lane];
    us4 v6 = Yv[(size_t)u6 + lane];
    us4 v7 = Yv[(size_t)u7 + lane];
    float w0 = wsel(e + 0, b1, b2, b3, s0, s1, s2, s3);
    float w1 = wsel(e + 1, b1, b2, b3, s0, s1, s2, s3);
    float w2 = wsel(e + 2, b1, b2, b3, s0, s1, s2, s3);
    float w3 = wsel(e + 3, b1, b2, b3, s0, s1, s2, s3);
    float w4 = wsel(e + 4, b1, b2, b3, s0, s1, s2, s3);
    float w5 = wsel(e + 5, b1, b2, b3, s0, s1, s2, s3);
    float w6 = wsel(e + 6, b1, b2, b3, s0, s1, s2, s3);
    float w7 = wsel(e + 7, b1, b2, b3, s0, s1, s2, s3);
    consume(v0, w0); consume(v1, w1); consume(v2, w2); consume(v3, w3);
    consume(v4, w4); consume(v5, w5); consume(v6, w6); consume(v7, w7);
  }
  for (; e + 4 <= b4; e += 4) {
    unsigned int u0 = sorted[e], u1 = sorted[e + 1], u2 = sorted[e + 2], u3 = sorted[e + 3];
    us4 v0 = Yv[(size_t)u0 + lane];
    us4 v1 = Yv[(size_t)u1 + lane];
    us4 v2 = Yv[(size_t)u2 + lane];
    us4 v3 = Yv[(size_t)u3 + lane];
    float w0 = wsel(e + 0, b1, b2, b3, s0, s1, s2, s3);
    float w1 = wsel(e + 1, b1, b2, b3, s0, s1, s2, s3);
    float w2 = wsel(e + 2, b1, b2, b3, s0, s1, s2, s3);
    float w3 = wsel(e + 3, b1, b2, b3, s0, s1, s2, s3);
    consume(v0, w0); consume(v1, w1); consume(v2, w2); consume(v3, w3);
  }
  for (; e < b4; ++e) {
    us4 v = Yv[(size_t)sorted[e] + lane];
    consume(v, wsel(e, b1, b2, b3, s0, s1, s2, s3));
  }

  float4 u0v;
  u0v.x = acc.x + bf2f(rt.x) + bi.x;
  u0v.y = acc.y + bf2f(rt.y) + bi.y;
  u0v.z = acc.z + bf2f(rt.z) + bi.z;
  u0v.w = acc.w + bf2f(rt.w) + bi.w;

  float p = u0v.x * w1v.x + u0v.y * w1v.y + u0v.z * w1v.z + u0v.w * w1v.w;
#pragma unroll
  for (int m2 = 32; m2 >= 1; m2 >>= 1) p += __shfl_xor(p, m2);
  float a = 1.0f / (1.0f + expf(-(p + axv + abp[0])));
  float b = 1.0f - a;
  float4 h;
  h.x = tanhf(u0v.x) * a + bf2f(xb.x) * b;
  h.y = tanhf(u0v.y) * a + bf2f(xb.y) * b;
  h.z = tanhf(u0v.z) * a + bf2f(xb.z) * b;
  h.w = tanhf(u0v.w) * a + bf2f(xb.w) * b;
  reinterpret_cast<float4*>(out + (size_t)dst * C)[lane] = h;
}

extern "C" void kernel_launch(void* const* d_in, const int* in_sizes, int n_in,
                              void* d_out, int out_size, void* d_ws, size_t ws_size,
                              hipStream_t stream) {
  const float* X     = (const float*)d_in[0];
  const int*   eidx  = (const int*)d_in[1];
  const int*   etype = (const int*)d_in[2];
  const float* rel   = (const float*)d_in[3];
  const float* root  = (const float*)d_in[4];
  const float* bias  = (const float*)d_in[5];
  const float* attw  = (const float*)d_in[6];
  const float* ab    = (const float*)d_in[7];
  float* out = (float*)d_out;

  int N = in_sizes[0] / C;                // 50000
  int E = in_sizes[2];                    // 800000
  int rowsPad = ((N + 127) / 128) * 128;  // 50048
  const int* esrc = eidx;
  const int* edst = eidx + E;
  int n4 = 4 * N;                         // (dst, relation) bucket count

  char* w = (char*)d_ws;
  size_t off = 0;
  auto alloc = [&](size_t bytes) -> void* {
    void* p = w + off;
    off += (bytes + 255) & ~(size_t)255;
    return p;
  };
  unsigned short* Y    = (unsigned short*)alloc((size_t)rowsPad * NOUT * 2);  // 128 MB
  unsigned short* Xbf  = (unsigned short*)alloc((size_t)rowsPad * C * 2);
  unsigned short* WT2  = (unsigned short*)alloc((size_t)NOUT * C * 2);
  float* ax2  = (float*)alloc((size_t)rowsPad * 4);
  int* cnt    = (int*)alloc((size_t)n4 * 4);
  int* rp     = (int*)alloc((size_t)(n4 + 1) * 4);
  int* rank   = (int*)alloc((size_t)E * 4);
  int* bsum   = (int*)alloc(2048);
  int* boffb  = (int*)alloc(2048);
  unsigned int* sorted = (unsigned int*)alloc((size_t)E * 4);

  hipMemsetAsync(cnt, 0, (size_t)n4 * 4, stream);
  int preBlocks = 80 + (rowsPad >> 2) + (E + 255) / 256;
  k_pre<<<preBlocks, 256, 0, stream>>>(X, rel, root, attw, edst, etype,
                                       Xbf, WT2, ax2, cnt, rank, N, rowsPad, E);
  int NB = (n4 + 511) / 512;
  k_scan1<<<NB, 512, 0, stream>>>(cnt, rp, bsum, n4);
  k_scan2<<<1, 64, 0, stream>>>(bsum, boffb, rp, NB, n4);
  k_scan3<<<NB, 512, 0, stream>>>(rp, boffb, n4);
  k_fill<<<(E + 255) / 256, 256, 0, stream>>>(esrc, edst, etype, rank, rp, sorted, E);
  k_gemm<<<(rowsPad / 128) * 10, 256, 0, stream>>>(Xbf, WT2, Y, rowsPad);
  k_gg<<<(N + 3) / 4, 256, 0, stream>>>(Y, sorted, rp, Xbf, bias, attw, ab, ax2, out, N);
}

// Round 18
// 220.095 us; speedup vs baseline: 1.5816x; 1.0080x over previous
//
#include <hip/hip_runtime.h>
#include <hip/hip_bf16.h>

#define C 256
#define NOUT 1280
#define BK 32

typedef __attribute__((ext_vector_type(8))) short bf16x8;
typedef __attribute__((ext_vector_type(4))) float f32x4;
typedef __attribute__((ext_vector_type(4))) unsigned short us4;

#define GLL16(g, l)                                                         \
  __builtin_amdgcn_global_load_lds(                                         \
      (const __attribute__((address_space(1))) void*)(g),                   \
      (__attribute__((address_space(3))) void*)(l), 16, 0, 0)

__device__ __forceinline__ float bf2f(unsigned short u) {
  return __uint_as_float(((unsigned int)u) << 16);
}
__device__ __forceinline__ unsigned short f2bf(float f) {
  unsigned int x = __float_as_uint(f);
  unsigned int lsb = (x >> 16) & 1u;
  x += 0x7fffu + lsb;  // round-to-nearest-even
  return (unsigned short)(x >> 16);
}

// Fused prep (cnt pre-zeroed by hipMemsetAsync).
// blocks [0,80): W transpose via LDS: WT2[n][k] = bf16(W_m[k][c]), n=m*256+c.
// [80, 80+rowsPad/4): X->bf16 rows + ax2[row] = dot(X,w2).
// rest: (dst,relation) histogram; the returned old value IS the edge's
// within-bucket rank -> stored for the atomic-free fill.
__global__ void k_pre(const float* __restrict__ X, const float* __restrict__ rel,
                      const float* __restrict__ root, const float* __restrict__ attw,
                      const int* __restrict__ edst, const int* __restrict__ etype,
                      unsigned short* __restrict__ Xbf, unsigned short* __restrict__ WT2,
                      float* __restrict__ ax2, int* __restrict__ cnt,
                      int* __restrict__ rank, int N, int rowsPad, int E) {
  __shared__ float tw[64][65];
  int b = blockIdx.x, t = threadIdx.x;
  if (b < 80) {
    int m = b >> 4, tile = b & 15;
    int ti = tile >> 2, tj = tile & 3;           // ti: k-tile, tj: c-tile
    const float* W = (m == 0) ? root : (rel + (size_t)(m - 1) * C * C);
    int row = t >> 2, cj = (t & 3) * 16;         // row = k within tile
    const float* src = W + (size_t)(ti * 64 + row) * C + tj * 64 + cj;
#pragma unroll
    for (int j = 0; j < 4; ++j) {
      float4 v = reinterpret_cast<const float4*>(src)[j];
      tw[row][cj + j * 4 + 0] = v.x;
      tw[row][cj + j * 4 + 1] = v.y;
      tw[row][cj + j * 4 + 2] = v.z;
      tw[row][cj + j * 4 + 3] = v.w;
    }
    __syncthreads();
    int c = t >> 2, k0 = (t & 3) * 16;           // c within tile
    int n = m * 256 + tj * 64 + c;
    unsigned short o[16];
#pragma unroll
    for (int k = 0; k < 16; ++k) o[k] = f2bf(tw[k0 + k][c]);
#pragma unroll
    for (int j = 0; j < 4; ++j)
      *reinterpret_cast<us4*>(WT2 + (size_t)n * C + ti * 64 + k0 + j * 4) =
          *reinterpret_cast<us4*>(&o[j * 4]);
  } else if (b < 80 + (rowsPad >> 2)) {
    int row = (b - 80) * 4 + (t >> 6);
    int lane = t & 63;
    if (row < N) {
      float4 v = reinterpret_cast<const float4*>(X + (size_t)row * C)[lane];
      float4 w2 = reinterpret_cast<const float4*>(attw + C)[lane];
      us4 o;
      o.x = f2bf(v.x); o.y = f2bf(v.y); o.z = f2bf(v.z); o.w = f2bf(v.w);
      reinterpret_cast<us4*>(Xbf)[(size_t)row * 64 + lane] = o;
      float p = v.x * w2.x + v.y * w2.y + v.z * w2.z + v.w * w2.w;
#pragma unroll
      for (int m2 = 32; m2 >= 1; m2 >>= 1) p += __shfl_xor(p, m2);
      if (lane == 0) ax2[row] = p;
    } else if (row < rowsPad) {
      us4 z; z.x = 0; z.y = 0; z.z = 0; z.w = 0;
      reinterpret_cast<us4*>(Xbf)[(size_t)row * 64 + lane] = z;
      if (lane == 0) ax2[row] = 0.f;
    }
  } else {
    int e = (b - 80 - (rowsPad >> 2)) * 256 + t;
    if (e < E) rank[e] = atomicAdd(cnt + edst[e] * 4 + etype[e], 1);
  }
}

__global__ void k_scan1(const int* __restrict__ cnt, int* __restrict__ rp,
                        int* __restrict__ bsum, int n) {
  __shared__ int s[512];
  int t = threadIdx.x;
  int i = blockIdx.x * 512 + t;
  int v = (i < n) ? cnt[i] : 0;
  s[t] = v;
  __syncthreads();
  for (int off = 1; off < 512; off <<= 1) {
    int add = (t >= off) ? s[t - off] : 0;
    __syncthreads();
    s[t] += add;
    __syncthreads();
  }
  if (i < n) rp[i] = s[t] - v;
  if (t == 511) bsum[blockIdx.x] = s[511];
}

__global__ void k_scan2(const int* __restrict__ bsum, int* __restrict__ boff,
                        int* __restrict__ rp, int nb, int n) {
  if (threadIdx.x == 0) {
    int run = 0;
    for (int b = 0; b < nb; ++b) { boff[b] = run; run += bsum[b]; }
    rp[n] = run;
  }
}

__global__ void k_scan3(int* __restrict__ rp, const int* __restrict__ boff, int n) {
  int i = blockIdx.x * 512 + threadIdx.x;
  if (i < n) rp[i] += boff[blockIdx.x];
}

// Atomic-free fill: pos = rp[bucket] + rank[e] (unique within bucket).
// Stores the fully-encoded Y offset (us4 units): src*320 + (r+1)*64.
__global__ void k_fill(const int* __restrict__ esrc, const int* __restrict__ edst,
                       const int* __restrict__ etype, const int* __restrict__ rank,
                       const int* __restrict__ rp, unsigned int* __restrict__ sorted,
                       int E) {
  int e = blockIdx.x * blockDim.x + threadIdx.x;
  if (e >= E) return;
  int d = edst[e];
  int r = etype[e];
  int pos = rp[d * 4 + r] + rank[e];
  sorted[pos] = (unsigned int)(esrc[e] * 320 + (r + 1) * 64);
}

// Y = Xbf @ WT2^T, M=rowsPad N=1280 K=256, Y bf16 [rowsPad][1280].
// 128x128 tile, 2-phase dbuf, GLL16 staging, 2-way-max XOR swizzle, XCD
// chunked swizzle, unrolled 8-step K loop, LDS-transposed coalesced epilogue.
__global__ __launch_bounds__(256) void k_gemm(
    const unsigned short* __restrict__ Xbf, const unsigned short* __restrict__ WT2,
    unsigned short* __restrict__ Y, int rowsPad) {
  __shared__ unsigned short smem[16384];          // 32KB
  unsigned short* ldsA = smem;                    // [2][4096]
  unsigned short* ldsB = smem + 8192;             // [2][4096]
  int tid = threadIdx.x;
  int wave = tid >> 6, lane = tid & 63;

  int nwg = gridDim.x, orig = blockIdx.x;
  int q = nwg >> 3, r = nwg & 7;
  int xcd = orig & 7, lin = orig >> 3;
  int wgid = (xcd < r ? xcd * (q + 1) : r * (q + 1) + (xcd - r) * q) + lin;
  int mblk = wgid / 10, nblk = wgid - mblk * 10;
  int row0 = mblk * 128, col0 = nblk * 128;
  int wr = wave >> 1, wc = wave & 1, lcol = lane & 15;

  const unsigned short* aSrc[2];
  const unsigned short* bSrc[2];
  int ldsOfs[2];
#pragma unroll
  for (int c2 = 0; c2 < 2; ++c2) {
    int off = (wave * 2 + c2) * 1024 + lane * 16;
    int rr = off >> 6;
    int lg8 = (((off >> 4) & 3) ^ ((rr >> 1) & 3)) * 8;
    aSrc[c2] = Xbf + (size_t)(row0 + rr) * C + lg8;
    bSrc[c2] = WT2 + (size_t)(col0 + rr) * C + lg8;
    ldsOfs[c2] = (wave * 2 + c2) * 1024;
  }

  int aoff[4], boff[4];
  int kb = (lane >> 4) * 16;
#pragma unroll
  for (int i = 0; i < 4; ++i) {
    int ar = wr * 64 + i * 16 + lcol;
    aoff[i] = ar * 64 + (kb ^ (((ar >> 1) & 3) << 4));
    int bc = wc * 64 + i * 16 + lcol;
    boff[i] = bc * 64 + (kb ^ (((bc >> 1) & 3) << 4));
  }

  f32x4 acc[4][4];
#pragma unroll
  for (int i = 0; i < 4; ++i)
#pragma unroll
    for (int j = 0; j < 4; ++j) {
      f32x4 z; z[0] = 0.f; z[1] = 0.f; z[2] = 0.f; z[3] = 0.f;
      acc[i][j] = z;
    }

  auto stage = [&](int buf, int ks) {
    int kofs = ks * BK;
#pragma unroll
    for (int c2 = 0; c2 < 2; ++c2) {
      GLL16(aSrc[c2] + kofs, (char*)(ldsA + buf * 4096) + ldsOfs[c2]);
      GLL16(bSrc[c2] + kofs, (char*)(ldsB + buf * 4096) + ldsOfs[c2]);
    }
  };

  stage(0, 0);
  __syncthreads();

#pragma unroll
  for (int ks = 0; ks < 8; ++ks) {
    int cur = ks & 1;
    if (ks + 1 < 8) stage(cur ^ 1, ks + 1);
    bf16x8 af[4], bfr[4];
#pragma unroll
    for (int i = 0; i < 4; ++i) {
      af[i]  = *reinterpret_cast<const bf16x8*>((const char*)(ldsA + cur * 4096) + aoff[i]);
      bfr[i] = *reinterpret_cast<const bf16x8*>((const char*)(ldsB + cur * 4096) + boff[i]);
    }
#pragma unroll
    for (int mr = 0; mr < 4; ++mr)
#pragma unroll
      for (int nc = 0; nc < 4; ++nc)
        acc[mr][nc] = __builtin_amdgcn_mfma_f32_16x16x32_bf16(af[mr], bfr[nc], acc[mr][nc], 0, 0, 0);
    __syncthreads();
  }

  int lrow4 = (lane >> 4) * 4;
#pragma unroll
  for (int mr = 0; mr < 4; ++mr)
#pragma unroll
    for (int nc = 0; nc < 4; ++nc)
#pragma unroll
      for (int reg = 0; reg < 4; ++reg) {
        int rr = wr * 64 + mr * 16 + lrow4 + reg;
        int cc = wc * 64 + nc * 16 + lcol;
        smem[rr * 128 + ((((cc >> 3) + rr) & 15) << 3) + (cc & 7)] =
            f2bf(acc[mr][nc][reg]);
      }
  __syncthreads();
#pragma unroll
  for (int rnd = 0; rnd < 8; ++rnd) {
    int rr = rnd * 16 + (tid >> 4);
    int g = tid & 15;
    int p = (g + rr) & 15;
    bf16x8 v = *reinterpret_cast<const bf16x8*>(smem + rr * 128 + p * 8);
    *reinterpret_cast<bf16x8*>(Y + (size_t)(row0 + rr) * NOUT + col0 + g * 8) = v;
  }
}

// Fused gather+gate, branch-free. Blend input read from Xbf (25.6MB bf16)
// instead of X fp32 -> less FETCH and less L3 pollution of Y.
__device__ __forceinline__ float wsel(int e, int b1, int b2, int b3,
                                      float s0, float s1, float s2, float s3) {
  return e < b1 ? s0 : (e < b2 ? s1 : (e < b3 ? s2 : s3));
}

__global__ __launch_bounds__(256, 4) void k_gg(
    const unsigned short* __restrict__ Y, const unsigned int* __restrict__ sorted,
    const int* __restrict__ rp, const unsigned short* __restrict__ Xbf,
    const float* __restrict__ bias, const float* __restrict__ attw,
    const float* __restrict__ abp, const float* __restrict__ ax2,
    float* __restrict__ out, int N) {
  int wave = threadIdx.x >> 6, lane = threadIdx.x & 63;
  int dst = blockIdx.x * 4 + wave;
  if (dst >= N) return;
  const us4* Yv = reinterpret_cast<const us4*>(Y);   // row stride 320 us4

  // independent far loads issued early
  us4 rt = Yv[(size_t)dst * 320 + lane];              // root slice (m=0)
  us4 xb = reinterpret_cast<const us4*>(Xbf)[(size_t)dst * 64 + lane];
  float4 bi = reinterpret_cast<const float4*>(bias)[lane];
  float4 w1v = reinterpret_cast<const float4*>(attw)[lane];
  float axv = ax2[dst];

  int b0 = rp[dst * 4 + 0], b1 = rp[dst * 4 + 1], b2 = rp[dst * 4 + 2],
      b3 = rp[dst * 4 + 3], b4 = rp[dst * 4 + 4];
  float s0 = 1.0f / (float)max(b1 - b0, 1);
  float s1 = 1.0f / (float)max(b2 - b1, 1);
  float s2 = 1.0f / (float)max(b3 - b2, 1);
  float s3 = 1.0f / (float)max(b4 - b3, 1);

  float4 acc = make_float4(0.f, 0.f, 0.f, 0.f);

  auto consume = [&](const us4& v, float wt) {
    acc.x += wt * bf2f(v.x);
    acc.y += wt * bf2f(v.y);
    acc.z += wt * bf2f(v.z);
    acc.w += wt * bf2f(v.w);
  };

  int e = b0;
  for (; e + 8 <= b4; e += 8) {
    unsigned int u0 = sorted[e],     u1 = sorted[e + 1], u2 = sorted[e + 2], u3 = sorted[e + 3];
    unsigned int u4 = sorted[e + 4], u5 = sorted[e + 5], u6 = sorted[e + 6], u7 = sorted[e + 7];
    us4 v0 = Yv[(size_t)u0 + lane];
    us4 v1 = Yv[(size_t)u1 + lane];
    us4 v2 = Yv[(size_t)u2 + lane];
    us4 v3 = Yv[(size_t)u3 + lane];
    us4 v4 = Yv[(size_t)u4 + lane];
    us4 v5 = Yv[(size_t)u5 + lane];
    us4 v6 = Yv[(size_t)u6 + lane];
    us4 v7 = Yv[(size_t)u7 + lane];
    float w0 = wsel(e + 0, b1, b2, b3, s0, s1, s2, s3);
    float w1 = wsel(e + 1, b1, b2, b3, s0, s1, s2, s3);
    float w2 = wsel(e + 2, b1, b2, b3, s0, s1, s2, s3);
    float w3 = wsel(e + 3, b1, b2, b3, s0, s1, s2, s3);
    float w4 = wsel(e + 4, b1, b2, b3, s0, s1, s2, s3);
    float w5 = wsel(e + 5, b1, b2, b3, s0, s1, s2, s3);
    float w6 = wsel(e + 6, b1, b2, b3, s0, s1, s2, s3);
    float w7 = wsel(e + 7, b1, b2, b3, s0, s1, s2, s3);
    consume(v0, w0); consume(v1, w1); consume(v2, w2); consume(v3, w3);
    consume(v4, w4); consume(v5, w5); consume(v6, w6); consume(v7, w7);
  }
  for (; e + 4 <= b4; e += 4) {
    unsigned int u0 = sorted[e], u1 = sorted[e + 1], u2 = sorted[e + 2], u3 = sorted[e + 3];
    us4 v0 = Yv[(size_t)u0 + lane];
    us4 v1 = Yv[(size_t)u1 + lane];
    us4 v2 = Yv[(size_t)u2 + lane];
    us4 v3 = Yv[(size_t)u3 + lane];
    float w0 = wsel(e + 0, b1, b2, b3, s0, s1, s2, s3);
    float w1 = wsel(e + 1, b1, b2, b3, s0, s1, s2, s3);
    float w2 = wsel(e + 2, b1, b2, b3, s0, s1, s2, s3);
    float w3 = wsel(e + 3, b1, b2, b3, s0, s1, s2, s3);
    consume(v0, w0); consume(v1, w1); consume(v2, w2); consume(v3, w3);
  }
  for (; e < b4; ++e) {
    us4 v = Yv[(size_t)sorted[e] + lane];
    consume(v, wsel(e, b1, b2, b3, s0, s1, s2, s3));
  }

  float4 u0v;
  u0v.x = acc.x + bf2f(rt.x) + bi.x;
  u0v.y = acc.y + bf2f(rt.y) + bi.y;
  u0v.z = acc.z + bf2f(rt.z) + bi.z;
  u0v.w = acc.w + bf2f(rt.w) + bi.w;

  float p = u0v.x * w1v.x + u0v.y * w1v.y + u0v.z * w1v.z + u0v.w * w1v.w;
#pragma unroll
  for (int m2 = 32; m2 >= 1; m2 >>= 1) p += __shfl_xor(p, m2);
  float a = 1.0f / (1.0f + expf(-(p + axv + abp[0])));
  float b = 1.0f - a;
  float4 h;
  h.x = tanhf(u0v.x) * a + bf2f(xb.x) * b;
  h.y = tanhf(u0v.y) * a + bf2f(xb.y) * b;
  h.z = tanhf(u0v.z) * a + bf2f(xb.z) * b;
  h.w = tanhf(u0v.w) * a + bf2f(xb.w) * b;
  reinterpret_cast<float4*>(out + (size_t)dst * C)[lane] = h;
}

extern "C" void kernel_launch(void* const* d_in, const int* in_sizes, int n_in,
                              void* d_out, int out_size, void* d_ws, size_t ws_size,
                              hipStream_t stream) {
  const float* X     = (const float*)d_in[0];
  const int*   eidx  = (const int*)d_in[1];
  const int*   etype = (const int*)d_in[2];
  const float* rel   = (const float*)d_in[3];
  const float* root  = (const float*)d_in[4];
  const float* bias  = (const float*)d_in[5];
  const float* attw  = (const float*)d_in[6];
  const float* ab    = (const float*)d_in[7];
  float* out = (float*)d_out;

  int N = in_sizes[0] / C;                // 50000
  int E = in_sizes[2];                    // 800000
  int rowsPad = ((N + 127) / 128) * 128;  // 50048
  const int* esrc = eidx;
  const int* edst = eidx + E;
  int n4 = 4 * N;                         // (dst, relation) bucket count

  char* w = (char*)d_ws;
  size_t off = 0;
  auto alloc = [&](size_t bytes) -> void* {
    void* p = w + off;
    off += (bytes + 255) & ~(size_t)255;
    return p;
  };
  unsigned short* Y    = (unsigned short*)alloc((size_t)rowsPad * NOUT * 2);  // 128 MB
  unsigned short* Xbf  = (unsigned short*)alloc((size_t)rowsPad * C * 2);
  unsigned short* WT2  = (unsigned short*)alloc((size_t)NOUT * C * 2);
  float* ax2  = (float*)alloc((size_t)rowsPad * 4);
  int* cnt    = (int*)alloc((size_t)n4 * 4);
  int* rp     = (int*)alloc((size_t)(n4 + 1) * 4);
  int* rank   = (int*)alloc((size_t)E * 4);
  int* bsum   = (int*)alloc(2048);
  int* boffb  = (int*)alloc(2048);
  unsigned int* sorted = (unsigned int*)alloc((size_t)E * 4);

  hipMemsetAsync(cnt, 0, (size_t)n4 * 4, stream);
  int preBlocks = 80 + (rowsPad >> 2) + (E + 255) / 256;
  k_pre<<<preBlocks, 256, 0, stream>>>(X, rel, root, attw, edst, etype,
                                       Xbf, WT2, ax2, cnt, rank, N, rowsPad, E);
  int NB = (n4 + 511) / 512;
  k_scan1<<<NB, 512, 0, stream>>>(cnt, rp, bsum, n4);
  k_scan2<<<1, 64, 0, stream>>>(bsum, boffb, rp, NB, n4);
  k_scan3<<<NB, 512, 0, stream>>>(rp, boffb, n4);
  k_fill<<<(E + 255) / 256, 256, 0, stream>>>(esrc, edst, etype, rank, rp, sorted, E);
  k_gemm<<<(rowsPad / 128) * 10, 256, 0, stream>>>(Xbf, WT2, Y, rowsPad);
  k_gg<<<(N + 3) / 4, 256, 0, stream>>>(Y, sorted, rp, Xbf, bias, attw, ab, ax2, out, N);
}